// Round 23
// baseline (289.374 us; speedup 1.0000x reference)
//
#include <hip/hip_runtime.h>

typedef unsigned short ushort_t;
typedef unsigned int uint_t;
typedef unsigned char uchar_t;
typedef __attribute__((ext_vector_type(8))) short short8;
typedef __attribute__((ext_vector_type(4))) float f32x4;
typedef __attribute__((ext_vector_type(2))) float f32x2;

#define B   128
#define Nv  256
#define Mn  12
#define Hd  128
#define Dd  3
#define Kk  2
#define AFd 82
#define BFd 6
#define BN  (B*Nv)   // 32768

enum { EPI_NONE = 0, EPI_LRELU = 1 };

__device__ __forceinline__ float lrelu(float x) { return fmaxf(x, 0.1f * x); }
__device__ __forceinline__ float frcp(float x) { return __builtin_amdgcn_rcpf(x); }
__device__ __forceinline__ float sigmoidf(float x) { return frcp(1.f + __expf(-x)); }
__device__ __forceinline__ float ftanh(float x) {
    const float xc = fminf(fmaxf(x, -15.f), 15.f);
    const float e = __expf(2.f * xc);
    return (e - 1.f) * frcp(e + 1.f);
}
__device__ __forceinline__ ushort_t f2b(float x) {
    uint_t u = __float_as_uint(x);
    return (ushort_t)((u + 0x7FFFu + ((u >> 16) & 1u)) >> 16);
}
__device__ __forceinline__ float b2f(ushort_t s) {
    return __uint_as_float(((uint_t)s) << 16);
}
__device__ __forceinline__ void b2f4(uint2 u, float* o) {
    o[0] = __uint_as_float((u.x & 0xFFFFu) << 16);
    o[1] = __uint_as_float(u.x & 0xFFFF0000u);
    o[2] = __uint_as_float((u.y & 0xFFFFu) << 16);
    o[3] = __uint_as_float(u.y & 0xFFFF0000u);
}
__device__ __forceinline__ uint_t pk2(float lo, float hi) {
    return (uint_t)f2b(lo) | ((uint_t)f2b(hi) << 16);
}
__device__ __forceinline__ float upk_lo(uint_t u) { return __uint_as_float((u & 0xFFFFu) << 16); }
__device__ __forceinline__ float upk_hi(uint_t u) { return __uint_as_float(u & 0xFFFF0000u); }
__device__ __forceinline__ uchar_t f2e8(float x) {
    return (uchar_t)(__builtin_amdgcn_cvt_pk_fp8_f32(x, 0.f, 0, false) & 0xFF);
}

// ---------------- fused weight prep (one launch) ----------------
struct PrepJob {
    const float* W;
    long sliceStride;
    int K, ldw, nPerSlice, Kspan, KpadRow, kDst, total, outOff, blockStart;
};
struct PrepJobs { PrepJob j[18]; int nJobs; };

__global__ __launch_bounds__(256) void k_prep_all(PrepJobs P, ushort_t* __restrict__ WT)
{
    int bid = blockIdx.x;
    int ji = 0;
    #pragma unroll 1
    while (ji + 1 < P.nJobs && P.j[ji + 1].blockStart <= bid) ++ji;
    const PrepJob J = P.j[ji];
    const int idx = (bid - J.blockStart) * 256 + threadIdx.x;
    if (idx >= J.total) return;
    const int n = idx / J.Kspan, k = idx % J.Kspan;
    const int slice = n / J.nPerSlice, nn = n % J.nPerSlice;
    float v = (k < J.K) ? J.W[(size_t)slice * J.sliceStride + (size_t)k * J.ldw + nn] : 0.f;
    WT[(size_t)J.outOff + (size_t)n * J.KpadRow + J.kDst + k] = f2b(v);
}

// qtab[d][j][h] (bf16) = sum_f init_bond[j,f] * U2_w[d][128+f][h]
__global__ __launch_bounds__(256) void k_qtab(const float* __restrict__ init_bond,
                                              const float* __restrict__ U2w,
                                              ushort_t* __restrict__ qt)
{
    const int d = blockIdx.x;
    const float* W = U2w + (size_t)d * (Hd + BFd) * Hd + (size_t)Hd * Hd;
    ushort_t* q = qt + (size_t)d * 12 * Hd;
    for (int idx = threadIdx.x; idx < 12 * Hd; idx += 256) {
        const int j = idx >> 7, h = idx & 127;
        float s = 0.f;
        #pragma unroll
        for (int f = 0; f < BFd; ++f) s += init_bond[j * BFd + f] * W[f * Hd + h];
        q[idx] = f2b(s);
    }
}

// ---------------- embed GEMM (fp32 gathered A, 64x128 tile) ----------------
template<int EPI, bool ABF, bool OBF>
__global__ __launch_bounds__(256) void mgemm(
    const void* __restrict__ A1v, int lda1, int K1,
    const int* __restrict__ rowidx,
    const ushort_t* __restrict__ Wt, int Kpad,
    const float* __restrict__ b1,
    void* __restrict__ outv, long ldo)
{
    const int t    = threadIdx.x;
    const int lane = t & 63;
    const int w    = t >> 6;
    const int wm   = w >> 1, wn = w & 1;
    const int lr   = lane & 15, lg = lane >> 4;
    const int row0 = blockIdx.x * 64;

    __shared__ ushort_t As[64 * 64];

    f32x4 acc[2][4];
    #pragma unroll
    for (int i = 0; i < 2; ++i)
        #pragma unroll
        for (int j = 0; j < 4; ++j)
            acc[i][j] = (f32x4){0.f, 0.f, 0.f, 0.f};

    const int r_st = t >> 2, q4 = t & 3;
    const int grow = row0 + r_st;
    const long arow = rowidx ? (long)rowidx[grow] : (long)grow;

    const int nck = Kpad >> 6;
    for (int ck = 0; ck < nck; ++ck) {
        if (ck) __syncthreads();
        {
            const int kb = ck * 64 + q4 * 16;
            union { ushort_t us[16]; uint4 qv[2]; } tmp;
            #pragma unroll
            for (int j = 0; j < 16; ++j) {
                const int kg = kb + j;
                ushort_t v = 0;
                if (kg < K1) {
                    if (ABF) v = ((const ushort_t*)A1v)[(size_t)arow * lda1 + kg];
                    else     v = f2b(((const float*)A1v)[(size_t)arow * lda1 + kg]);
                }
                tmp.us[j] = v;
            }
            #pragma unroll
            for (int j = 0; j < 2; ++j) {
                int byte = r_st * 128 + q4 * 32 + j * 16;
                byte ^= ((r_st & 7) << 4);
                *(uint4*)((char*)As + byte) = tmp.qv[j];
            }
        }
        __syncthreads();
        #pragma unroll
        for (int ks = 0; ks < 64; ks += 32) {
            short8 af[2], bfr[4];
            #pragma unroll
            for (int mf = 0; mf < 2; ++mf) {
                const int row = wm * 32 + mf * 16 + lr;
                int byte = row * 128 + (ks + lg * 8) * 2;
                byte ^= ((row & 7) << 4);
                af[mf] = *(const short8*)((const char*)As + byte);
            }
            #pragma unroll
            for (int nf = 0; nf < 4; ++nf) {
                const int col = wn * 64 + nf * 16 + lr;
                bfr[nf] = *(const short8*)(Wt + (size_t)col * Kpad + ck * 64 + ks + lg * 8);
            }
            #pragma unroll
            for (int mf = 0; mf < 2; ++mf)
                #pragma unroll
                for (int nf = 0; nf < 4; ++nf)
                    acc[mf][nf] = __builtin_amdgcn_mfma_f32_16x16x32_bf16(
                        af[mf], bfr[nf], acc[mf][nf], 0, 0, 0);
        }
    }

    #pragma unroll
    for (int mf = 0; mf < 2; ++mf) {
        #pragma unroll
        for (int nf = 0; nf < 4; ++nf) {
            const int c = wn * 64 + nf * 16 + lr;
            #pragma unroll
            for (int reg = 0; reg < 4; ++reg) {
                const int r = wm * 32 + mf * 16 + lg * 4 + reg;
                const size_t row = (size_t)row0 + r;
                float v = acc[mf][nf][reg];
                if (b1) v += b1[c];
                if constexpr (EPI == EPI_LRELU) v = lrelu(v);
                const size_t oidx = row * ldo + c;
                if (OBF) ((ushort_t*)outv)[oidx] = f2b(v);
                else     ((float*)outv)[oidx] = v;
            }
        }
    }
}

// ---------------- fused attention-score + P projection (global-B, LDS-A) -----
// blockIdx.y == 0: BOTH score slices (A staged once); == 1: P projection (fp8)
__global__ __launch_bounds__(256) void k_tdp(
    const ushort_t* __restrict__ vfb,
    const ushort_t* __restrict__ Wt,
    const float* __restrict__ waB,
    const float* __restrict__ u2B,
    const float* __restrict__ sf,
    const float* __restrict__ wbmmW,
    const float* __restrict__ wbmmB,
    float* __restrict__ a_out,
    uchar_t* __restrict__ Pout)
{
    const int t = threadIdx.x;
    const int lane = t & 63, w = t >> 6;
    const int wm = w >> 1, wn = w & 1;
    const int lr = lane & 15, lg = lane >> 4;
    const int row0 = blockIdx.x * 64;
    const int path = blockIdx.y;
    const int b = row0 >> 8;

    __shared__ ushort_t As[64 * 128];
    __shared__ float EUs[2][128], EBb[2][128];
    __shared__ float red[64][2];

    {
        const int r_st = t >> 2, q4 = t & 3;
        const ushort_t* src = vfb + (size_t)(row0 + r_st) * Hd + q4 * 32;
        #pragma unroll
        for (int j = 0; j < 4; ++j) {
            uint4 v = ((const uint4*)src)[j];
            int byte = r_st * 256 + q4 * 64 + j * 16;
            byte ^= ((r_st & 7) << 4);
            *(uint4*)((char*)As + byte) = v;
        }
    }
    if (path == 0) {
        const int s = t >> 7, h = t & 127;
        EUs[s][h] = sf[b * Hd + h] * wbmmW[s * Hd + h];
        EBb[s][h] = waB[s * Hd + h];
    }
    __syncthreads();

    f32x4 acc[2][4];

    if (path == 1) {
        const ushort_t* Wty = Wt + (size_t)2 * 16384;
        #pragma unroll
        for (int i = 0; i < 2; ++i)
            #pragma unroll
            for (int j = 0; j < 4; ++j)
                acc[i][j] = (f32x4){0.f, 0.f, 0.f, 0.f};
        #pragma unroll
        for (int kk = 0; kk < 128; kk += 32) {
            short8 af[2], bfr[4];
            #pragma unroll
            for (int nf = 0; nf < 4; ++nf) {
                const int col = wn * 64 + nf * 16 + lr;
                bfr[nf] = *(const short8*)(Wty + (size_t)col * 128 + kk + lg * 8);
            }
            #pragma unroll
            for (int mf = 0; mf < 2; ++mf) {
                const int row = wm * 32 + mf * 16 + lr;
                int byte = row * 256 + (kk + lg * 8) * 2;
                byte ^= ((row & 7) << 4);
                af[mf] = *(const short8*)((const char*)As + byte);
            }
            #pragma unroll
            for (int mf = 0; mf < 2; ++mf)
                #pragma unroll
                for (int nf = 0; nf < 4; ++nf)
                    acc[mf][nf] = __builtin_amdgcn_mfma_f32_16x16x32_bf16(
                        af[mf], bfr[nf], acc[mf][nf], 0, 0, 0);
        }
        #pragma unroll
        for (int mf = 0; mf < 2; ++mf)
            #pragma unroll
            for (int nf = 0; nf < 4; ++nf) {
                const int c = wn * 64 + nf * 16 + lr;
                #pragma unroll
                for (int reg = 0; reg < 4; ++reg) {
                    const int r = wm * 32 + mf * 16 + lg * 4 + reg;
                    Pout[(size_t)(row0 + r) * Hd + c] = f2e8(acc[mf][nf][reg] + u2B[c]);
                }
            }
        return;
    }

    // ---- both score slices, A staged once ----
    #pragma unroll 1
    for (int s = 0; s < 2; ++s) {
        const ushort_t* Wty = Wt + (size_t)s * 16384;
        #pragma unroll
        for (int i = 0; i < 2; ++i)
            #pragma unroll
            for (int j = 0; j < 4; ++j)
                acc[i][j] = (f32x4){0.f, 0.f, 0.f, 0.f};
        #pragma unroll
        for (int kk = 0; kk < 128; kk += 32) {
            short8 af[2], bfr[4];
            #pragma unroll
            for (int nf = 0; nf < 4; ++nf) {
                const int col = wn * 64 + nf * 16 + lr;
                bfr[nf] = *(const short8*)(Wty + (size_t)col * 128 + kk + lg * 8);
            }
            #pragma unroll
            for (int mf = 0; mf < 2; ++mf) {
                const int row = wm * 32 + mf * 16 + lr;
                int byte = row * 256 + (kk + lg * 8) * 2;
                byte ^= ((row & 7) << 4);
                af[mf] = *(const short8*)((const char*)As + byte);
            }
            #pragma unroll
            for (int mf = 0; mf < 2; ++mf)
                #pragma unroll
                for (int nf = 0; nf < 4; ++nf)
                    acc[mf][nf] = __builtin_amdgcn_mfma_f32_16x16x32_bf16(
                        af[mf], bfr[nf], acc[mf][nf], 0, 0, 0);
        }
        #pragma unroll
        for (int mf = 0; mf < 2; ++mf) {
            #pragma unroll
            for (int reg = 0; reg < 4; ++reg) {
                float p = 0.f;
                #pragma unroll
                for (int nf = 0; nf < 4; ++nf) {
                    const int c = wn * 64 + nf * 16 + lr;
                    p += ftanh(acc[mf][nf][reg] + EBb[s][c]) * EUs[s][c];
                }
                p += __shfl_xor(p, 1); p += __shfl_xor(p, 2);
                p += __shfl_xor(p, 4); p += __shfl_xor(p, 8);
                if (lr == 0) red[wm * 32 + mf * 16 + lg * 4 + reg][wn] = p;
            }
        }
        __syncthreads();
        if (t < 64) {
            const int gr = row0 + t;
            a_out[(size_t)(gr >> 8) * 512 + (size_t)s * 256 + (gr & 255)] =
                red[t][0] + red[t][1] + wbmmB[s];
        }
        __syncthreads();
    }
}

// ---------------- multi-output GEMV building blocks (fp32 weights) ----------------
__device__ __forceinline__ void gemv1(const float* __restrict__ W0, const float* __restrict__ x0,
                                      int ldw, int off, int K,
                                      float (*red)[8][32][4],
                                      float* __restrict__ y0, int t)
{
    const int gq = t & 31, hs = t >> 5;
    const int hn = K >> 3;
    f32x4 a0 = (f32x4){0.f,0.f,0.f,0.f};
    const float* Wp0 = W0 + off + (size_t)gq * 4;
    const int h0 = hs * hn;
    #pragma unroll 8
    for (int i = 0; i < hn; ++i) {
        const float4 w0 = *(const float4*)&Wp0[(size_t)(h0 + i) * ldw];
        const float v0 = x0[h0 + i];
        a0.x = fmaf(v0, w0.x, a0.x); a0.y = fmaf(v0, w0.y, a0.y);
        a0.z = fmaf(v0, w0.z, a0.z); a0.w = fmaf(v0, w0.w, a0.w);
    }
    *(f32x4*)&red[0][hs][gq][0] = a0;
    __syncthreads();
    if (t < 128) {
        float s0 = 0.f;
        #pragma unroll
        for (int p = 0; p < 8; ++p) s0 += red[0][p][t >> 2][t & 3];
        y0[t] = s0;
    }
    __syncthreads();
}

__device__ __forceinline__ void gemv2(const float* __restrict__ W0, const float* __restrict__ x0,
                                      const float* __restrict__ W1, const float* __restrict__ x1,
                                      int ldw, int off, int K,
                                      float (*red)[8][32][4],
                                      float* __restrict__ y0, float* __restrict__ y1, int t)
{
    const int gq = t & 31, hs = t >> 5;
    const int hn = K >> 3;
    f32x4 a0 = (f32x4){0.f,0.f,0.f,0.f}, a1 = (f32x4){0.f,0.f,0.f,0.f};
    const float* Wp0 = W0 + off + (size_t)gq * 4;
    const float* Wp1 = W1 + off + (size_t)gq * 4;
    const int h0 = hs * hn;
    #pragma unroll 4
    for (int i = 0; i < hn; ++i) {
        const float4 w0 = *(const float4*)&Wp0[(size_t)(h0 + i) * ldw];
        const float4 w1 = *(const float4*)&Wp1[(size_t)(h0 + i) * ldw];
        const float v0 = x0[h0 + i], v1 = x1[h0 + i];
        a0.x = fmaf(v0, w0.x, a0.x); a0.y = fmaf(v0, w0.y, a0.y);
        a0.z = fmaf(v0, w0.z, a0.z); a0.w = fmaf(v0, w0.w, a0.w);
        a1.x = fmaf(v1, w1.x, a1.x); a1.y = fmaf(v1, w1.y, a1.y);
        a1.z = fmaf(v1, w1.z, a1.z); a1.w = fmaf(v1, w1.w, a1.w);
    }
    *(f32x4*)&red[0][hs][gq][0] = a0;
    *(f32x4*)&red[1][hs][gq][0] = a1;
    __syncthreads();
    if (t < 128) {
        float s0 = 0.f, s1 = 0.f;
        #pragma unroll
        for (int p = 0; p < 8; ++p) {
            s0 += red[0][p][t >> 2][t & 3];
            s1 += red[1][p][t >> 2][t & 3];
        }
        y0[t] = s0; y1[t] = s1;
    }
    __syncthreads();
}

__device__ __forceinline__ void gemv3(const float* __restrict__ W0, const float* __restrict__ x0,
                                      const float* __restrict__ W1, const float* __restrict__ x1,
                                      const float* __restrict__ W2, const float* __restrict__ x2,
                                      int ldw, int off, int K,
                                      float (*red)[8][32][4],
                                      float* __restrict__ y0, float* __restrict__ y1,
                                      float* __restrict__ y2, int t)
{
    const int gq = t & 31, hs = t >> 5;
    const int hn = K >> 3;
    f32x4 a0 = (f32x4){0.f,0.f,0.f,0.f}, a1 = (f32x4){0.f,0.f,0.f,0.f}, a2 = (f32x4){0.f,0.f,0.f,0.f};
    const float* Wp0 = W0 + off + (size_t)gq * 4;
    const float* Wp1 = W1 + off + (size_t)gq * 4;
    const float* Wp2 = W2 + off + (size_t)gq * 4;
    const int h0 = hs * hn;
    #pragma unroll 4
    for (int i = 0; i < hn; ++i) {
        const float4 w0 = *(const float4*)&Wp0[(size_t)(h0 + i) * ldw];
        const float4 w1 = *(const float4*)&Wp1[(size_t)(h0 + i) * ldw];
        const float4 w2 = *(const float4*)&Wp2[(size_t)(h0 + i) * ldw];
        const float v0 = x0[h0 + i], v1 = x1[h0 + i], v2 = x2[h0 + i];
        a0.x = fmaf(v0, w0.x, a0.x); a0.y = fmaf(v0, w0.y, a0.y);
        a0.z = fmaf(v0, w0.z, a0.z); a0.w = fmaf(v0, w0.w, a0.w);
        a1.x = fmaf(v1, w1.x, a1.x); a1.y = fmaf(v1, w1.y, a1.y);
        a1.z = fmaf(v1, w1.z, a1.z); a1.w = fmaf(v1, w1.w, a1.w);
        a2.x = fmaf(v2, w2.x, a2.x); a2.y = fmaf(v2, w2.y, a2.y);
        a2.z = fmaf(v2, w2.z, a2.z); a2.w = fmaf(v2, w2.w, a2.w);
    }
    *(f32x4*)&red[0][hs][gq][0] = a0;
    *(f32x4*)&red[1][hs][gq][0] = a1;
    *(f32x4*)&red[2][hs][gq][0] = a2;
    __syncthreads();
    if (t < 128) {
        float s0 = 0.f, s1 = 0.f, s2 = 0.f;
        #pragma unroll
        for (int p = 0; p < 8; ++p) {
            s0 += red[0][p][t >> 2][t & 3];
            s1 += red[1][p][t >> 2][t & 3];
            s2 += red[2][p][t >> 2][t & 3];
        }
        y0[t] = s0; y1[t] = s1; y2[t] = s2;
    }
    __syncthreads();
}

// ---------------- fused {supernode chain | NEI gather} in one launch ----------
__global__ __launch_bounds__(256) void k_gsup(
    const float* __restrict__ a_buf, const float* __restrict__ vmask,
    const ushort_t* __restrict__ vfb,
    const float* __restrict__ sf_in,
    const float* __restrict__ Wm, const float* __restrict__ bm,
    const float* __restrict__ Wm2s, const float* __restrict__ bm2s,
    const float* __restrict__ Ws2m, const float* __restrict__ bs2m,
    const float* __restrict__ Wsup, const float* __restrict__ bsup,
    const float* __restrict__ Wzm2, const float* __restrict__ bzm2,
    const float* __restrict__ Wzs1, const float* __restrict__ bzs1,
    const float* __restrict__ Wzs2, const float* __restrict__ bzs2,
    const float* __restrict__ gwih, const float* __restrict__ gwhh,
    const float* __restrict__ gbih, const float* __restrict__ gbhh,
    float* __restrict__ s2m_g, float* __restrict__ czm2_g,
    float* __restrict__ sf_out,
    const uchar_t* __restrict__ P8, const ushort_t* __restrict__ qt,
    const int* __restrict__ aadj, const int* __restrict__ badj,
    const int* __restrict__ edge, const float* __restrict__ nmask,
    ushort_t* __restrict__ nei)
{
    const int t = threadIdx.x;

    if (blockIdx.x >= B) {
        // ================= gather branch (512 blocks, 64 rows each) ========
        __shared__ ushort_t aiS[64 * Mn];
        __shared__ ushort_t eiS[64 * Mn];
        __shared__ ushort_t mkS[64 * Mn];
        const int row0 = (blockIdx.x - B) * 64;
        for (int i = t; i < 64 * Mn; i += 256) {
            const int r = i / Mn, m = i - r * Mn;
            const long g = (long)(row0 + r) * Mn + m;
            aiS[i] = (ushort_t)aadj[g];
            eiS[i] = (ushort_t)edge[badj[g]];
            mkS[i] = f2b(nmask[g]);
        }
        __syncthreads();
        #pragma unroll 1
        for (int it = 0; it < 4; ++it) {
            const int idx = it * 256 + t;
            const int r = idx >> 4, h0 = (idx & 15) * 8;
            float a8[8] = {0.f,0.f,0.f,0.f,0.f,0.f,0.f,0.f};
            #pragma unroll
            for (int m = 0; m < Mn; ++m) {
                const int ai = aiS[r * Mn + m];
                const float mk = b2f(mkS[r * Mn + m]);
                const uint2 pv = *(const uint2*)&P8[(size_t)ai * Hd + h0];
                const uint4 qv = *(const uint4*)&qt[(size_t)eiS[r * Mn + m] * Hd + h0];
                const f32x2 p01 = __builtin_amdgcn_cvt_pk_f32_fp8((int)pv.x, false);
                const f32x2 p23 = __builtin_amdgcn_cvt_pk_f32_fp8((int)pv.x, true);
                const f32x2 p45 = __builtin_amdgcn_cvt_pk_f32_fp8((int)pv.y, false);
                const f32x2 p67 = __builtin_amdgcn_cvt_pk_f32_fp8((int)pv.y, true);
                const float pf[8] = {p01[0], p01[1], p23[0], p23[1], p45[0], p45[1], p67[0], p67[1]};
                const ushort_t* qq = (const ushort_t*)&qv;
                #pragma unroll
                for (int e = 0; e < 8; ++e) {
                    const float v = pf[e] + b2f(qq[e]);
                    a8[e] = fmaf(mk, lrelu(v), a8[e]);
                }
            }
            ushort_t o8[8];
            #pragma unroll
            for (int e = 0; e < 8; ++e) o8[e] = f2b(a8[e]);
            *(uint4*)&nei[(size_t)(row0 + r) * Hd + h0] = *(const uint4*)o8;
        }
        return;
    }

    // ================= supernode branch (B blocks) =========================
    const int b = blockIdx.x;
    const int wid = t >> 6, lane = t & 63;
    __shared__ float red[3][8][32][4];
    __shared__ float att0[256], att1[256];
    __shared__ float sfl[128], tbA[128], tbB[128], mv[256];
    __shared__ float ms2[128], s2ml[128], ssl[128], hsl[128];
    __shared__ float tmp1[128], tmp2[128], tmp3[128];
    __shared__ float gib[384], ghb[384];
    __shared__ float saS[2];
    __shared__ float lm[4][2], ls[4][2];

    const float v0 = a_buf[(size_t)b * 512 + t];
    const float v1 = a_buf[(size_t)b * 512 + 256 + t];
    const float vm = vmask[b * Nv + t];
    float m0 = v0, m1 = v1;
    #pragma unroll
    for (int o = 1; o < 64; o <<= 1) {
        m0 = fmaxf(m0, __shfl_xor(m0, o));
        m1 = fmaxf(m1, __shfl_xor(m1, o));
    }
    if (lane == 0) { lm[wid][0] = m0; lm[wid][1] = m1; }
    __syncthreads();
    m0 = fmaxf(fmaxf(lm[0][0], lm[1][0]), fmaxf(lm[2][0], lm[3][0]));
    m1 = fmaxf(fmaxf(lm[0][1], lm[1][1]), fmaxf(lm[2][1], lm[3][1]));
    const float e0v = __expf(v0 - m0) * vm;
    const float e1v = __expf(v1 - m1) * vm;
    float s0 = e0v, s1 = e1v;
    #pragma unroll
    for (int o = 1; o < 64; o <<= 1) {
        s0 += __shfl_xor(s0, o);
        s1 += __shfl_xor(s1, o);
    }
    if (lane == 0) { ls[wid][0] = s0; ls[wid][1] = s1; }
    if (t < 128) sfl[t] = sf_in[b * Hd + t];
    __syncthreads();
    s0 = ls[0][0] + ls[1][0] + ls[2][0] + ls[3][0];
    s1 = ls[0][1] + ls[1][1] + ls[2][1] + ls[3][1];
    att0[t] = e0v * frcp(s0 + 1e-6f);
    att1[t] = e1v * frcp(s1 + 1e-6f);
    if (t == 0) { saS[0] = s0 * frcp(s0 + 1e-6f); saS[1] = s1 * frcp(s1 + 1e-6f); }
    __syncthreads();

    {
        const int hq = t & 31, ns = t >> 5;
        f32x4 a0 = (f32x4){0.f,0.f,0.f,0.f}, a1 = (f32x4){0.f,0.f,0.f,0.f};
        const ushort_t* base = vfb + (size_t)b * Nv * Hd + hq * 4;
        #pragma unroll 8
        for (int i = 0; i < 32; ++i) {
            const int n = ns * 32 + i;
            float xv[4];
            b2f4(*(const uint2*)&base[(size_t)n * Hd], xv);
            const float w0 = att0[n], w1 = att1[n];
            a0.x = fmaf(w0, xv[0], a0.x); a0.y = fmaf(w0, xv[1], a0.y);
            a0.z = fmaf(w0, xv[2], a0.z); a0.w = fmaf(w0, xv[3], a0.w);
            a1.x = fmaf(w1, xv[0], a1.x); a1.y = fmaf(w1, xv[1], a1.y);
            a1.z = fmaf(w1, xv[2], a1.z); a1.w = fmaf(w1, xv[3], a1.w);
        }
        *(f32x4*)&red[0][ns][hq][0] = a0;
        *(f32x4*)&red[1][ns][hq][0] = a1;
        __syncthreads();
        if (t < 128) {
            float u0 = 0.f, u1 = 0.f;
            #pragma unroll
            for (int p = 0; p < 8; ++p) {
                u0 += red[0][p][t >> 2][t & 3];
                u1 += red[1][p][t >> 2][t & 3];
            }
            tbA[t] = u0; tbB[t] = u1;
        }
        __syncthreads();
    }

    gemv2(Wm, tbA, Wm + Hd * Hd, tbB, Hd, 0, Hd, red, mv, mv + 128, t);
    mv[t] += saS[t >> 7] * bm[t];
    __syncthreads();

    gemv1(Wm2s, mv, Hd, 0, 2 * Hd, red, tmp1, t);
    if (t < 128) ms2[t] = ftanh(tmp1[t] + bm2s[t]);
    __syncthreads();

    gemv2(Ws2m, sfl, Wsup, sfl, Hd, 0, Hd, red, tmp1, tmp2, t);
    if (t < 128) {
        const float v = ftanh(tmp1[t] + bs2m[t]);
        s2ml[t] = v; s2m_g[b * Hd + t] = v;
        ssl[t] = ftanh(tmp2[t] + bsup[t]);
    }
    __syncthreads();

    gemv3(Wzm2, s2ml, Wzs1, ssl, Wzs2, ms2, Hd, 0, Hd, red, tmp1, tmp2, tmp3, t);
    if (t < 128) {
        czm2_g[b * Hd + t] = tmp1[t] + bzm2[t];
        const float zs = sigmoidf(tmp2[t] + bzs1[t] + tmp3[t] + bzs2[t]);
        hsl[t] = (1.f - zs) * ssl[t] + zs * ms2[t];
    }
    __syncthreads();

    #pragma unroll 1
    for (int c = 0; c < 3; ++c)
        gemv2(gwih, hsl, gwhh, sfl, 3 * Hd, c * Hd, Hd, red, gib + c * Hd, ghb + c * Hd, t);
    if (t < 128) {
        const float r = sigmoidf(gib[t] + gbih[t] + ghb[t] + gbhh[t]);
        const float z = sigmoidf(gib[128 + t] + gbih[128 + t] + ghb[128 + t] + gbhh[128 + t]);
        const float n = ftanh(gib[256 + t] + gbih[256 + t] + r * (ghb[256 + t] + gbhh[256 + t]));
        sf_out[b * Hd + t] = (1.f - z) * n + z * sfl[t];
    }
}

// ---------------- MEGA: 64-row tile, 8 waves (512 thr), 3 barriers -----------
// waves: wm = w>>2 (2 row halves), wn = w&3 (4 col groups of 32)
// As[64][256]: cols 0..127 = VF, cols 128..255 = NEI (read-only after stage)
// Ms[64][128]: MS buffer; Hs[64][128]: HID buffer (each written once)
__global__ __launch_bounds__(512) void k_mega(
    const ushort_t* __restrict__ vfb,
    const ushort_t* __restrict__ nei,
    const ushort_t* __restrict__ wt_u1,    // 128 cols, Kpad 256
    const ushort_t* __restrict__ wt_zm1,   // 128 cols, Kpad 128
    const ushort_t* __restrict__ wt_rz,    // 256 cols, Kpad 256 (k<128 wih/HID, k>=128 whh/VF)
    const ushort_t* __restrict__ wt_inn,   // 128 cols, Kpad 128 (HID)
    const ushort_t* __restrict__ wt_hn,    // 128 cols, Kpad 128 (VF)
    const float* __restrict__ u1b,
    const float* __restrict__ zm1b,
    const float* __restrict__ bih, const float* __restrict__ bhh,
    const float* __restrict__ czm2, const float* __restrict__ s2m,
    void* __restrict__ outv, const int finalFp32)
{
    const int t = threadIdx.x;
    const int lane = t & 63;
    const int w = t >> 6;          // 0..7
    const int wm = w >> 2;         // 0..1 (row half)
    const int wn = w & 3;          // 0..3 (col group)
    const int lr = lane & 15, lg = lane >> 4;
    const int row0 = blockIdx.x * 64;
    const int b = row0 >> 8;

    __shared__ ushort_t As[64 * 256];       // 32 KB (VF | NEI, read-only)
    __shared__ ushort_t Ms[64 * 128];       // 16 KB (MS)
    __shared__ ushort_t Hs[64 * 128];       // 16 KB (HID)

    // ---- stage VF -> cols 0..127, NEI -> cols 128..255 (512 threads) ----
    {
        const int r_st = t >> 3, q8 = t & 7;
        const ushort_t* srcV = vfb + (size_t)(row0 + r_st) * Hd + q8 * 16;
        const ushort_t* srcN = nei + (size_t)(row0 + r_st) * Hd + q8 * 16;
        uint4 v0 = ((const uint4*)srcV)[0];
        uint4 v1 = ((const uint4*)srcV)[1];
        uint4 n0 = ((const uint4*)srcN)[0];
        uint4 n1 = ((const uint4*)srcN)[1];
        int bV0 = (r_st * 512 + q8 * 32)            ^ ((r_st & 7) << 4);
        int bV1 = (r_st * 512 + q8 * 32 + 16)       ^ ((r_st & 7) << 4);
        int bN0 = (r_st * 512 + 256 + q8 * 32)      ^ ((r_st & 7) << 4);
        int bN1 = (r_st * 512 + 256 + q8 * 32 + 16) ^ ((r_st & 7) << 4);
        *(uint4*)((char*)As + bV0) = v0;
        *(uint4*)((char*)As + bV1) = v1;
        *(uint4*)((char*)As + bN0) = n0;
        *(uint4*)((char*)As + bN1) = n1;
    }
    __syncthreads();                        // (1) stage done

    f32x4 acc[2][2];

#define ZERO_ACC2() { _Pragma("unroll") for (int i = 0; i < 2; ++i) _Pragma("unroll") for (int j = 0; j < 2; ++j) acc[i][j] = (f32x4){0.f,0.f,0.f,0.f}; }
#define AF_L32(LC) (*(const short8*)((const char*)As + ((((wm * 32 + mf * 16 + lr) * 512 + ((LC) + lg * 8) * 2)) ^ (((wm * 32 + mf * 16 + lr) & 7) << 4))))
#define AF_MH(BUF, LC) (*(const short8*)((const char*)(BUF) + ((((wm * 32 + mf * 16 + lr) * 256 + ((LC) + lg * 8) * 2)) ^ (((wm * 32 + mf * 16 + lr) & 7) << 4))))
#define GEMM_PASS32(WG, KPADW, KTOT, A_EXPR) { \
        ZERO_ACC2(); \
        _Pragma("unroll") \
        for (int kk = 0; kk < (KTOT); kk += 32) { \
            short8 af[2], bfv[2]; \
            _Pragma("unroll") \
            for (int nf = 0; nf < 2; ++nf) \
                bfv[nf] = *(const short8*)((WG) + (size_t)(wn * 32 + nf * 16 + lr) * (KPADW) + kk + lg * 8); \
            _Pragma("unroll") \
            for (int mf = 0; mf < 2; ++mf) \
                af[mf] = (A_EXPR); \
            _Pragma("unroll") \
            for (int mf = 0; mf < 2; ++mf) \
                _Pragma("unroll") \
                for (int nf = 0; nf < 2; ++nf) \
                    acc[mf][nf] = __builtin_amdgcn_mfma_f32_16x16x32_bf16(af[mf], bfv[nf], acc[mf][nf], 0, 0, 0); \
        } }

    // ---- U1: MS = lrelu([VF|NEI]@Wu1 + b) -> Ms (fresh buffer) ----
    GEMM_PASS32(wt_u1, 256, 256, AF_L32(kk));
    #pragma unroll
    for (int mf = 0; mf < 2; ++mf)
        #pragma unroll
        for (int nf = 0; nf < 2; ++nf) {
            const int c = wn * 32 + nf * 16 + lr;
            const float bb = u1b[c];
            #pragma unroll
            for (int reg = 0; reg < 4; ++reg) {
                const int row = wm * 32 + mf * 16 + lg * 4 + reg;
                int byte = (row * 256 + c * 2) ^ ((row & 7) << 4);
                *(ushort_t*)((char*)Ms + byte) = f2b(lrelu(acc[mf][nf][reg] + bb));
            }
        }
    __syncthreads();                        // (2) MS ready

    // ---- ZMAIN: z = sig(MS@Wzm1 + b + czm2); HID = (1-z)*MS + z*s2m -> Hs ----
    GEMM_PASS32(wt_zm1, 128, 128, AF_MH(Ms, kk));
    #pragma unroll
    for (int mf = 0; mf < 2; ++mf)
        #pragma unroll
        for (int nf = 0; nf < 2; ++nf) {
            const int c = wn * 32 + nf * 16 + lr;
            const float bb = zm1b[c] + czm2[b * Hd + c];
            const float s2 = s2m[b * Hd + c];
            #pragma unroll
            for (int reg = 0; reg < 4; ++reg) {
                const int row = wm * 32 + mf * 16 + lg * 4 + reg;
                int byte = (row * 256 + c * 2) ^ ((row & 7) << 4);
                const float ms = b2f(*(const ushort_t*)((const char*)Ms + byte));
                const float z = sigmoidf(acc[mf][nf][reg] + bb);
                *(ushort_t*)((char*)Hs + byte) = f2b((1.f - z) * ms + z * s2);
            }
        }
    __syncthreads();                        // (3) HID ready — no more barriers

    // ---- GRU gates (packed bf16 intermediates) ----
    uint_t innp[2][2][2], hnp[2][2][2];
    GEMM_PASS32(wt_inn, 128, 128, AF_MH(Hs, kk));
    #pragma unroll
    for (int mf = 0; mf < 2; ++mf)
        #pragma unroll
        for (int nf = 0; nf < 2; ++nf) {
            const int c = wn * 32 + nf * 16 + lr;
            const float bb = bih[256 + c];
            innp[mf][nf][0] = pk2(acc[mf][nf][0] + bb, acc[mf][nf][1] + bb);
            innp[mf][nf][1] = pk2(acc[mf][nf][2] + bb, acc[mf][nf][3] + bb);
        }
    GEMM_PASS32(wt_hn, 128, 128, AF_L32(kk));
    #pragma unroll
    for (int mf = 0; mf < 2; ++mf)
        #pragma unroll
        for (int nf = 0; nf < 2; ++nf) {
            const int c = wn * 32 + nf * 16 + lr;
            const float bb = bhh[256 + c];
            hnp[mf][nf][0] = pk2(acc[mf][nf][0] + bb, acc[mf][nf][1] + bb);
            hnp[mf][nf][1] = pk2(acc[mf][nf][2] + bb, acc[mf][nf][3] + bb);
        }
    // r = sig([HID|VF]@Wr + b); n = tanh(inn + r*hn)
    GEMM_PASS32(wt_rz, 256, 256, (kk < 128) ? AF_MH(Hs, kk) : AF_L32(kk - 128));
    #pragma unroll
    for (int mf = 0; mf < 2; ++mf)
        #pragma unroll
        for (int nf = 0; nf < 2; ++nf) {
            const int c = wn * 32 + nf * 16 + lr;
            const float bb = bih[c] + bhh[c];
            const float r0 = sigmoidf(acc[mf][nf][0] + bb);
            const float r1 = sigmoidf(acc[mf][nf][1] + bb);
            const float r2 = sigmoidf(acc[mf][nf][2] + bb);
            const float r3 = sigmoidf(acc[mf][nf][3] + bb);
            const float n0 = ftanh(upk_lo(innp[mf][nf][0]) + r0 * upk_lo(hnp[mf][nf][0]));
            const float n1 = ftanh(upk_hi(innp[mf][nf][0]) + r1 * upk_hi(hnp[mf][nf][0]));
            const float n2 = ftanh(upk_lo(innp[mf][nf][1]) + r2 * upk_lo(hnp[mf][nf][1]));
            const float n3 = ftanh(upk_hi(innp[mf][nf][1]) + r3 * upk_hi(hnp[mf][nf][1]));
            innp[mf][nf][0] = pk2(n0, n1);
            innp[mf][nf][1] = pk2(n2, n3);
        }
    // z + combine + store (hprev from As VF region, cols 0..127)
    GEMM_PASS32(wt_rz + 128 * 256, 256, 256, (kk < 128) ? AF_MH(Hs, kk) : AF_L32(kk - 128));
    #pragma unroll
    for (int mf = 0; mf < 2; ++mf)
        #pragma unroll
        for (int nf = 0; nf < 2; ++nf) {
            const int c = wn * 32 + nf * 16 + lr;
            const float bb = bih[128 + c] + bhh[128 + c];
            #pragma unroll
            for (int reg = 0; reg < 4; ++reg) {
                const int rl = wm * 32 + mf * 16 + lg * 4 + reg;
                const float z = sigmoidf(acc[mf][nf][reg] + bb);
                const uint_t np = innp[mf][nf][reg >> 1];
                const float n = (reg & 1) ? upk_hi(np) : upk_lo(np);
                int byte = (rl * 512 + c * 2) ^ ((rl & 7) << 4);
                const float h = b2f(*(const ushort_t*)((const char*)As + byte));
                const float o = (1.f - z) * n + z * h;
                const size_t oidx = (size_t)(row0 + rl) * Hd + c;
                if (finalFp32) ((float*)outv)[oidx] = o;
                else           ((ushort_t*)outv)[oidx] = f2b(o);
            }
        }
#undef GEMM_PASS32
#undef ZERO_ACC2
#undef AF_L32
#undef AF_MH
}

// sf[b,h] = sum_n vf[b,n,h]*vmask[b,n]  (bf16 vf)
__global__ __launch_bounds__(256) void k_sfv(const ushort_t* __restrict__ vfb,
                                             const float* __restrict__ vmask,
                                             float* __restrict__ sf)
{
    const int b = blockIdx.x, t = threadIdx.x;
    __shared__ float vm[256];
    __shared__ float red[8][32][4];
    vm[t] = vmask[b * Nv + t];
    __syncthreads();
    const int hq = t & 31, ns = t >> 5;
    f32x4 acc = (f32x4){0.f,0.f,0.f,0.f};
    const ushort_t* base = vfb + (size_t)b * Nv * Hd + hq * 4;
    #pragma unroll 8
    for (int i = 0; i < 32; ++i) {
        const int n = ns * 32 + i;
        float xv[4];
        b2f4(*(const uint2*)&base[(size_t)n * Hd], xv);
        const float w = vm[n];
        acc.x = fmaf(w, xv[0], acc.x); acc.y = fmaf(w, xv[1], acc.y);
        acc.z = fmaf(w, xv[2], acc.z); acc.w = fmaf(w, xv[3], acc.w);
    }
    *(f32x4*)&red[ns][hq][0] = acc;
    __syncthreads();
    if (t < 128) {
        float s = 0.f;
        #pragma unroll
        for (int p = 0; p < 8; ++p) s += red[p][t >> 2][t & 3];
        sf[b * Hd + t] = s;
    }
}

extern "C" void kernel_launch(void* const* d_in, const int* in_sizes, int n_in,
                              void* d_out, int out_size, void* d_ws, size_t ws_size,
                              hipStream_t stream)
{
    (void)in_sizes; (void)n_in; (void)out_size;

    const float* vertex_mask = (const float*)d_in[1];
    const int*   vertex      = (const int*)d_in[2];
    const int*   edge        = (const int*)d_in[3];
    const int*   atom_adj    = (const int*)d_in[4];
    const int*   bond_adj    = (const int*)d_in[5];
    const float* nbs_mask    = (const float*)d_in[6];
    const float* init_atom   = (const float*)d_in[7];
    const float* init_bond   = (const float*)d_in[8];
    const float* emb_w  = (const float*)d_in[9];
    const float* emb_b  = (const float*)d_in[10];
    const float* Wa_w   = (const float*)d_in[11];
    const float* Wa_b   = (const float*)d_in[12];
    const float* Wbmm_w = (const float*)d_in[13];
    const float* Wbmm_b = (const float*)d_in[14];
    const float* Wm_w   = (const float*)d_in[15];
    const float* Wm_b   = (const float*)d_in[16];
    const float* Wm2s_w = (const float*)d_in[17];
    const float* Wm2s_b = (const float*)d_in[18];
    const float* Ws2m_w = (const float*)d_in[19];
    const float* Ws2m_b = (const float*)d_in[20];
    const float* Wsup_w = (const float*)d_in[21];
    const float* Wsup_b = (const float*)d_in[22];
    const float* Wzm1_w = (const float*)d_in[23];
    const float* Wzm1_b = (const float*)d_in[24];
    const float* Wzm2_w = (const float*)d_in[25];
    const float* Wzm2_b = (const float*)d_in[26];
    const float* Wzs1_w = (const float*)d_in[27];
    const float* Wzs1_b = (const float*)d_in[28];
    const float* Wzs2_w = (const float*)d_in[29];
    const float* Wzs2_b = (const float*)d_in[30];
    const float* U2_w   = (const float*)d_in[31];
    const float* U2_b   = (const float*)d_in[32];
    const float* U1_w   = (const float*)d_in[33];
    const float* U1_b   = (const float*)d_in[34];
    const float* gm_wih = (const float*)d_in[35];
    const float* gm_whh = (const float*)d_in[36];
    const float* gm_bih = (const float*)d_in[37];
    const float* gm_bhh = (const float*)d_in[38];
    const float* gs_wih = (const float*)d_in[39];
    const float* gs_whh = (const float*)d_in[40];
    const float* gs_bih = (const float*)d_in[41];
    const float* gs_bhh = (const float*)d_in[42];

    const size_t MB = 1u << 20;
    if (ws_size < 40 * MB) return;

    char* base = (char*)d_ws;
    ushort_t* VF0 = (ushort_t*)base;               // 8 MB
    ushort_t* VF1 = (ushort_t*)(base + 8 * MB);    // 8 MB
    uchar_t*  P8  = (uchar_t*)(base + 16 * MB);    // 4 MB (fp8 e4m3)
    ushort_t* NEI = (ushort_t*)(base + 20 * MB);   // 8 MB
    ushort_t* WT  = (ushort_t*)(base + 28 * MB);   // ~0.82 MB
    ushort_t* QT  = (ushort_t*)(base + 30 * MB);   // 3*12*128 bf16
    float*    S   = (float*)(base + 31 * MB);

    float* sfA    = S;
    float* sfB    = S + 16384;
    float* a_buf  = S + 32768;
    float* s2m    = S + 98304;
    float* c_zm2  = S + 114688;

    float* X1 = (float*)d_out;
    float* sf_final = X1 + (size_t)BN * Hd;

    const int OFF_EMB = 0;
    const int PERD = 98304;
    const int OFF_L0 = 16384;
    const int OFF_RZ = OFF_L0 + 3 * PERD;
    const int OFF_NH = OFF_RZ + 65536;

    PrepJobs PJ;
    int nj = 0, blk0 = 0;
    auto addJob = [&](const float* W, int K, int ldw, long sStride, int nPer,
                      int Kspan, int KpadRow, int kDst, int ncols, int outOff) {
        PrepJob& J = PJ.j[nj++];
        J.W = W; J.K = K; J.ldw = ldw; J.sliceStride = sStride; J.nPerSlice = nPer;
        J.Kspan = Kspan; J.KpadRow = KpadRow; J.kDst = kDst;
        J.total = ncols * Kspan; J.outOff = outOff; J.blockStart = blk0;
        blk0 += (J.total + 255) / 256;
    };
    addJob(emb_w, AFd, Hd, 0, Hd, 128, 128, 0, 128, OFF_EMB);
    for (int d = 0; d < Dd; ++d) {
        const int o = OFF_L0 + d * PERD;
        addJob(Wa_w + (long)d * Kk * Hd * Hd, Hd, Hd, (long)Hd * Hd, Hd, 128, 128, 0, 256, o);
        addJob(U2_w + (long)d * (Hd + BFd) * Hd, Hd, Hd, 0, Hd, 128, 128, 0, 128, o + 32768);
        addJob(U1_w + (long)d * 2 * Hd * Hd, 2 * Hd, Hd, 0, Hd, 256, 256, 0, 128, o + 49152);
        addJob(Wzm1_w + (long)d * Hd * Hd, Hd, Hd, 0, Hd, 128, 128, 0, 128, o + 81920);
    }
    addJob(gm_wih, Hd, 3 * Hd, 0, 256, 128, 256, 0,   256, OFF_RZ);
    addJob(gm_whh, Hd, 3 * Hd, 0, 256, 128, 256, 128, 256, OFF_RZ);
    addJob(gm_wih + 256, Hd, 3 * Hd, 0, 128, 128, 128, 0, 128, OFF_NH);
    addJob(gm_whh + 256, Hd, 3 * Hd, 0, 128, 128, 128, 0, 128, OFF_NH + 16384);
    PJ.nJobs = nj;
    k_prep_all<<<dim3(blk0), dim3(256), 0, stream>>>(PJ, WT);
    k_qtab<<<dim3(Dd), dim3(256), 0, stream>>>(init_bond, U2_w, QT);

    const dim3 blk(256);
    const dim3 g1(BN / 64, 1);

    // embed -> VF0 (bf16)
    mgemm<EPI_LRELU, false, true><<<g1, blk, 0, stream>>>(
        init_atom, AFd, AFd, vertex,
        WT + OFF_EMB, 128, emb_b, VF0, Hd);
    k_sfv<<<dim3(B), blk, 0, stream>>>(VF0, vertex_mask, sfA);

    for (int d = 0; d < Dd; ++d) {
        ushort_t* vin  = (d & 1) ? VF1 : VF0;
        ushort_t* vout = (d & 1) ? VF0 : VF1;
        float* sin  = (d & 1) ? sfB : sfA;
        float* sout = (d == Dd - 1) ? sf_final : ((d & 1) ? sfA : sfB);

        const int o = OFF_L0 + d * PERD;

        // scores (y=0: both k slices, A staged once) + P projection fp8 (y=1)
        k_tdp<<<dim3(BN / 64, 2), blk, 0, stream>>>(
            vin, WT + o,
            Wa_b + (long)d * Kk * Hd, U2_b + (long)d * Hd,
            sin, Wbmm_w + (long)d * Kk * Hd, Wbmm_b + (long)d * Kk,
            a_buf, P8);

        // fused {supernode chain | NEI gather} — independent work, one launch
        k_gsup<<<dim3(B + BN / 64), blk, 0, stream>>>(
            a_buf, vertex_mask, vin, sin,
            Wm_w + (long)d * Kk * Hd * Hd, Wm_b + (long)d * Kk * Hd,
            Wm2s_w + (long)d * Kk * Hd * Hd, Wm2s_b + (long)d * Hd,
            Ws2m_w + (long)d * Hd * Hd, Ws2m_b + (long)d * Hd,
            Wsup_w + (long)d * Hd * Hd, Wsup_b + (long)d * Hd,
            Wzm2_w + (long)d * Hd * Hd, Wzm2_b + (long)d * Hd,
            Wzs1_w + (long)d * Hd * Hd, Wzs1_b + (long)d * Hd,
            Wzs2_w + (long)d * Hd * Hd, Wzs2_b + (long)d * Hd,
            gs_wih, gs_whh, gs_bih, gs_bhh,
            s2m, c_zm2, sout,
            P8, QT + (size_t)d * 12 * Hd,
            atom_adj, bond_adj, edge, nbs_mask, NEI);

        // MEGA: U1 -> ZMAIN -> GRU main -> vf_out (64-row, 8 waves, 3 barriers)
        k_mega<<<g1, dim3(512), 0, stream>>>(
            vin, NEI,
            WT + o + 49152, WT + o + 81920,
            WT + OFF_RZ, WT + OFF_NH, WT + OFF_NH + 16384,
            U1_b + (long)d * Hd, Wzm1_b + (long)d * Hd,
            gm_bih, gm_bhh,
            c_zm2, s2m,
            (d == Dd - 1) ? (void*)X1 : (void*)vout, (d == Dd - 1) ? 1 : 0);
    }
}

// Round 24
// 282.496 us; speedup vs baseline: 1.0243x; 1.0243x over previous
//
#include <hip/hip_runtime.h>

typedef unsigned short ushort_t;
typedef unsigned int uint_t;
typedef unsigned char uchar_t;
typedef __attribute__((ext_vector_type(8))) short short8;
typedef __attribute__((ext_vector_type(4))) float f32x4;
typedef __attribute__((ext_vector_type(2))) float f32x2;

#define B   128
#define Nv  256
#define Mn  12
#define Hd  128
#define Dd  3
#define Kk  2
#define AFd 82
#define BFd 6
#define BN  (B*Nv)   // 32768

enum { EPI_NONE = 0, EPI_LRELU = 1 };

__device__ __forceinline__ float lrelu(float x) { return fmaxf(x, 0.1f * x); }
__device__ __forceinline__ float frcp(float x) { return __builtin_amdgcn_rcpf(x); }
__device__ __forceinline__ float sigmoidf(float x) { return frcp(1.f + __expf(-x)); }
__device__ __forceinline__ float ftanh(float x) {
    const float xc = fminf(fmaxf(x, -15.f), 15.f);
    const float e = __expf(2.f * xc);
    return (e - 1.f) * frcp(e + 1.f);
}
__device__ __forceinline__ ushort_t f2b(float x) {
    uint_t u = __float_as_uint(x);
    return (ushort_t)((u + 0x7FFFu + ((u >> 16) & 1u)) >> 16);
}
__device__ __forceinline__ float b2f(ushort_t s) {
    return __uint_as_float(((uint_t)s) << 16);
}
__device__ __forceinline__ void b2f4(uint2 u, float* o) {
    o[0] = __uint_as_float((u.x & 0xFFFFu) << 16);
    o[1] = __uint_as_float(u.x & 0xFFFF0000u);
    o[2] = __uint_as_float((u.y & 0xFFFFu) << 16);
    o[3] = __uint_as_float(u.y & 0xFFFF0000u);
}
__device__ __forceinline__ uint_t pk2(float lo, float hi) {
    return (uint_t)f2b(lo) | ((uint_t)f2b(hi) << 16);
}
__device__ __forceinline__ float upk_lo(uint_t u) { return __uint_as_float((u & 0xFFFFu) << 16); }
__device__ __forceinline__ float upk_hi(uint_t u) { return __uint_as_float(u & 0xFFFF0000u); }
__device__ __forceinline__ uchar_t f2e8(float x) {
    return (uchar_t)(__builtin_amdgcn_cvt_pk_fp8_f32(x, 0.f, 0, false) & 0xFF);
}

// ---------------- fused weight prep (one launch) ----------------
struct PrepJob {
    const float* W;
    long sliceStride;
    int K, ldw, nPerSlice, Kspan, KpadRow, kDst, total, outOff, blockStart;
};
struct PrepJobs { PrepJob j[18]; int nJobs; };

__global__ __launch_bounds__(256) void k_prep_all(PrepJobs P, ushort_t* __restrict__ WT)
{
    int bid = blockIdx.x;
    int ji = 0;
    #pragma unroll 1
    while (ji + 1 < P.nJobs && P.j[ji + 1].blockStart <= bid) ++ji;
    const PrepJob J = P.j[ji];
    const int idx = (bid - J.blockStart) * 256 + threadIdx.x;
    if (idx >= J.total) return;
    const int n = idx / J.Kspan, k = idx % J.Kspan;
    const int slice = n / J.nPerSlice, nn = n % J.nPerSlice;
    float v = (k < J.K) ? J.W[(size_t)slice * J.sliceStride + (size_t)k * J.ldw + nn] : 0.f;
    WT[(size_t)J.outOff + (size_t)n * J.KpadRow + J.kDst + k] = f2b(v);
}

// qtab[d][j][h] (bf16) = sum_f init_bond[j,f] * U2_w[d][128+f][h]
__global__ __launch_bounds__(256) void k_qtab(const float* __restrict__ init_bond,
                                              const float* __restrict__ U2w,
                                              ushort_t* __restrict__ qt)
{
    const int d = blockIdx.x;
    const float* W = U2w + (size_t)d * (Hd + BFd) * Hd + (size_t)Hd * Hd;
    ushort_t* q = qt + (size_t)d * 12 * Hd;
    for (int idx = threadIdx.x; idx < 12 * Hd; idx += 256) {
        const int j = idx >> 7, h = idx & 127;
        float s = 0.f;
        #pragma unroll
        for (int f = 0; f < BFd; ++f) s += init_bond[j * BFd + f] * W[f * Hd + h];
        q[idx] = f2b(s);
    }
}

// ---------------- embed GEMM (fp32 gathered A, 64x128 tile) ----------------
template<int EPI, bool ABF, bool OBF>
__global__ __launch_bounds__(256) void mgemm(
    const void* __restrict__ A1v, int lda1, int K1,
    const int* __restrict__ rowidx,
    const ushort_t* __restrict__ Wt, int Kpad,
    const float* __restrict__ b1,
    void* __restrict__ outv, long ldo)
{
    const int t    = threadIdx.x;
    const int lane = t & 63;
    const int w    = t >> 6;
    const int wm   = w >> 1, wn = w & 1;
    const int lr   = lane & 15, lg = lane >> 4;
    const int row0 = blockIdx.x * 64;

    __shared__ ushort_t As[64 * 64];

    f32x4 acc[2][4];
    #pragma unroll
    for (int i = 0; i < 2; ++i)
        #pragma unroll
        for (int j = 0; j < 4; ++j)
            acc[i][j] = (f32x4){0.f, 0.f, 0.f, 0.f};

    const int r_st = t >> 2, q4 = t & 3;
    const int grow = row0 + r_st;
    const long arow = rowidx ? (long)rowidx[grow] : (long)grow;

    const int nck = Kpad >> 6;
    for (int ck = 0; ck < nck; ++ck) {
        if (ck) __syncthreads();
        {
            const int kb = ck * 64 + q4 * 16;
            union { ushort_t us[16]; uint4 qv[2]; } tmp;
            #pragma unroll
            for (int j = 0; j < 16; ++j) {
                const int kg = kb + j;
                ushort_t v = 0;
                if (kg < K1) {
                    if (ABF) v = ((const ushort_t*)A1v)[(size_t)arow * lda1 + kg];
                    else     v = f2b(((const float*)A1v)[(size_t)arow * lda1 + kg]);
                }
                tmp.us[j] = v;
            }
            #pragma unroll
            for (int j = 0; j < 2; ++j) {
                int byte = r_st * 128 + q4 * 32 + j * 16;
                byte ^= ((r_st & 7) << 4);
                *(uint4*)((char*)As + byte) = tmp.qv[j];
            }
        }
        __syncthreads();
        #pragma unroll
        for (int ks = 0; ks < 64; ks += 32) {
            short8 af[2], bfr[4];
            #pragma unroll
            for (int mf = 0; mf < 2; ++mf) {
                const int row = wm * 32 + mf * 16 + lr;
                int byte = row * 128 + (ks + lg * 8) * 2;
                byte ^= ((row & 7) << 4);
                af[mf] = *(const short8*)((const char*)As + byte);
            }
            #pragma unroll
            for (int nf = 0; nf < 4; ++nf) {
                const int col = wn * 64 + nf * 16 + lr;
                bfr[nf] = *(const short8*)(Wt + (size_t)col * Kpad + ck * 64 + ks + lg * 8);
            }
            #pragma unroll
            for (int mf = 0; mf < 2; ++mf)
                #pragma unroll
                for (int nf = 0; nf < 4; ++nf)
                    acc[mf][nf] = __builtin_amdgcn_mfma_f32_16x16x32_bf16(
                        af[mf], bfr[nf], acc[mf][nf], 0, 0, 0);
        }
    }

    #pragma unroll
    for (int mf = 0; mf < 2; ++mf) {
        #pragma unroll
        for (int nf = 0; nf < 4; ++nf) {
            const int c = wn * 64 + nf * 16 + lr;
            #pragma unroll
            for (int reg = 0; reg < 4; ++reg) {
                const int r = wm * 32 + mf * 16 + lg * 4 + reg;
                const size_t row = (size_t)row0 + r;
                float v = acc[mf][nf][reg];
                if (b1) v += b1[c];
                if constexpr (EPI == EPI_LRELU) v = lrelu(v);
                const size_t oidx = row * ldo + c;
                if (OBF) ((ushort_t*)outv)[oidx] = f2b(v);
                else     ((float*)outv)[oidx] = v;
            }
        }
    }
}

// ---------------- fused attention-score + P projection (global-B, LDS-A) -----
// blockIdx.y == 0: BOTH score slices (A staged once); == 1: P projection (fp8)
__global__ __launch_bounds__(256) void k_tdp(
    const ushort_t* __restrict__ vfb,
    const ushort_t* __restrict__ Wt,
    const float* __restrict__ waB,
    const float* __restrict__ u2B,
    const float* __restrict__ sf,
    const float* __restrict__ wbmmW,
    const float* __restrict__ wbmmB,
    float* __restrict__ a_out,
    uchar_t* __restrict__ Pout)
{
    const int t = threadIdx.x;
    const int lane = t & 63, w = t >> 6;
    const int wm = w >> 1, wn = w & 1;
    const int lr = lane & 15, lg = lane >> 4;
    const int row0 = blockIdx.x * 64;
    const int path = blockIdx.y;
    const int b = row0 >> 8;

    __shared__ ushort_t As[64 * 128];
    __shared__ float EUs[2][128], EBb[2][128];
    __shared__ float red[64][2];

    {
        const int r_st = t >> 2, q4 = t & 3;
        const ushort_t* src = vfb + (size_t)(row0 + r_st) * Hd + q4 * 32;
        #pragma unroll
        for (int j = 0; j < 4; ++j) {
            uint4 v = ((const uint4*)src)[j];
            int byte = r_st * 256 + q4 * 64 + j * 16;
            byte ^= ((r_st & 7) << 4);
            *(uint4*)((char*)As + byte) = v;
        }
    }
    if (path == 0) {
        const int s = t >> 7, h = t & 127;
        EUs[s][h] = sf[b * Hd + h] * wbmmW[s * Hd + h];
        EBb[s][h] = waB[s * Hd + h];
    }
    __syncthreads();

    f32x4 acc[2][4];

    if (path == 1) {
        const ushort_t* Wty = Wt + (size_t)2 * 16384;
        #pragma unroll
        for (int i = 0; i < 2; ++i)
            #pragma unroll
            for (int j = 0; j < 4; ++j)
                acc[i][j] = (f32x4){0.f, 0.f, 0.f, 0.f};
        #pragma unroll
        for (int kk = 0; kk < 128; kk += 32) {
            short8 af[2], bfr[4];
            #pragma unroll
            for (int nf = 0; nf < 4; ++nf) {
                const int col = wn * 64 + nf * 16 + lr;
                bfr[nf] = *(const short8*)(Wty + (size_t)col * 128 + kk + lg * 8);
            }
            #pragma unroll
            for (int mf = 0; mf < 2; ++mf) {
                const int row = wm * 32 + mf * 16 + lr;
                int byte = row * 256 + (kk + lg * 8) * 2;
                byte ^= ((row & 7) << 4);
                af[mf] = *(const short8*)((const char*)As + byte);
            }
            #pragma unroll
            for (int mf = 0; mf < 2; ++mf)
                #pragma unroll
                for (int nf = 0; nf < 4; ++nf)
                    acc[mf][nf] = __builtin_amdgcn_mfma_f32_16x16x32_bf16(
                        af[mf], bfr[nf], acc[mf][nf], 0, 0, 0);
        }
        #pragma unroll
        for (int mf = 0; mf < 2; ++mf)
            #pragma unroll
            for (int nf = 0; nf < 4; ++nf) {
                const int c = wn * 64 + nf * 16 + lr;
                #pragma unroll
                for (int reg = 0; reg < 4; ++reg) {
                    const int r = wm * 32 + mf * 16 + lg * 4 + reg;
                    Pout[(size_t)(row0 + r) * Hd + c] = f2e8(acc[mf][nf][reg] + u2B[c]);
                }
            }
        return;
    }

    // ---- both score slices, A staged once ----
    #pragma unroll 1
    for (int s = 0; s < 2; ++s) {
        const ushort_t* Wty = Wt + (size_t)s * 16384;
        #pragma unroll
        for (int i = 0; i < 2; ++i)
            #pragma unroll
            for (int j = 0; j < 4; ++j)
                acc[i][j] = (f32x4){0.f, 0.f, 0.f, 0.f};
        #pragma unroll
        for (int kk = 0; kk < 128; kk += 32) {
            short8 af[2], bfr[4];
            #pragma unroll
            for (int nf = 0; nf < 4; ++nf) {
                const int col = wn * 64 + nf * 16 + lr;
                bfr[nf] = *(const short8*)(Wty + (size_t)col * 128 + kk + lg * 8);
            }
            #pragma unroll
            for (int mf = 0; mf < 2; ++mf) {
                const int row = wm * 32 + mf * 16 + lr;
                int byte = row * 256 + (kk + lg * 8) * 2;
                byte ^= ((row & 7) << 4);
                af[mf] = *(const short8*)((const char*)As + byte);
            }
            #pragma unroll
            for (int mf = 0; mf < 2; ++mf)
                #pragma unroll
                for (int nf = 0; nf < 4; ++nf)
                    acc[mf][nf] = __builtin_amdgcn_mfma_f32_16x16x32_bf16(
                        af[mf], bfr[nf], acc[mf][nf], 0, 0, 0);
        }
        #pragma unroll
        for (int mf = 0; mf < 2; ++mf) {
            #pragma unroll
            for (int reg = 0; reg < 4; ++reg) {
                float p = 0.f;
                #pragma unroll
                for (int nf = 0; nf < 4; ++nf) {
                    const int c = wn * 64 + nf * 16 + lr;
                    p += ftanh(acc[mf][nf][reg] + EBb[s][c]) * EUs[s][c];
                }
                p += __shfl_xor(p, 1); p += __shfl_xor(p, 2);
                p += __shfl_xor(p, 4); p += __shfl_xor(p, 8);
                if (lr == 0) red[wm * 32 + mf * 16 + lg * 4 + reg][wn] = p;
            }
        }
        __syncthreads();
        if (t < 64) {
            const int gr = row0 + t;
            a_out[(size_t)(gr >> 8) * 512 + (size_t)s * 256 + (gr & 255)] =
                red[t][0] + red[t][1] + wbmmB[s];
        }
        __syncthreads();
    }
}

// ---------------- multi-output GEMV building blocks (fp32 weights) ----------------
__device__ __forceinline__ void gemv1(const float* __restrict__ W0, const float* __restrict__ x0,
                                      int ldw, int off, int K,
                                      float (*red)[8][32][4],
                                      float* __restrict__ y0, int t)
{
    const int gq = t & 31, hs = t >> 5;
    const int hn = K >> 3;
    f32x4 a0 = (f32x4){0.f,0.f,0.f,0.f};
    const float* Wp0 = W0 + off + (size_t)gq * 4;
    const int h0 = hs * hn;
    #pragma unroll 8
    for (int i = 0; i < hn; ++i) {
        const float4 w0 = *(const float4*)&Wp0[(size_t)(h0 + i) * ldw];
        const float v0 = x0[h0 + i];
        a0.x = fmaf(v0, w0.x, a0.x); a0.y = fmaf(v0, w0.y, a0.y);
        a0.z = fmaf(v0, w0.z, a0.z); a0.w = fmaf(v0, w0.w, a0.w);
    }
    *(f32x4*)&red[0][hs][gq][0] = a0;
    __syncthreads();
    if (t < 128) {
        float s0 = 0.f;
        #pragma unroll
        for (int p = 0; p < 8; ++p) s0 += red[0][p][t >> 2][t & 3];
        y0[t] = s0;
    }
    __syncthreads();
}

__device__ __forceinline__ void gemv2(const float* __restrict__ W0, const float* __restrict__ x0,
                                      const float* __restrict__ W1, const float* __restrict__ x1,
                                      int ldw, int off, int K,
                                      float (*red)[8][32][4],
                                      float* __restrict__ y0, float* __restrict__ y1, int t)
{
    const int gq = t & 31, hs = t >> 5;
    const int hn = K >> 3;
    f32x4 a0 = (f32x4){0.f,0.f,0.f,0.f}, a1 = (f32x4){0.f,0.f,0.f,0.f};
    const float* Wp0 = W0 + off + (size_t)gq * 4;
    const float* Wp1 = W1 + off + (size_t)gq * 4;
    const int h0 = hs * hn;
    #pragma unroll 4
    for (int i = 0; i < hn; ++i) {
        const float4 w0 = *(const float4*)&Wp0[(size_t)(h0 + i) * ldw];
        const float4 w1 = *(const float4*)&Wp1[(size_t)(h0 + i) * ldw];
        const float v0 = x0[h0 + i], v1 = x1[h0 + i];
        a0.x = fmaf(v0, w0.x, a0.x); a0.y = fmaf(v0, w0.y, a0.y);
        a0.z = fmaf(v0, w0.z, a0.z); a0.w = fmaf(v0, w0.w, a0.w);
        a1.x = fmaf(v1, w1.x, a1.x); a1.y = fmaf(v1, w1.y, a1.y);
        a1.z = fmaf(v1, w1.z, a1.z); a1.w = fmaf(v1, w1.w, a1.w);
    }
    *(f32x4*)&red[0][hs][gq][0] = a0;
    *(f32x4*)&red[1][hs][gq][0] = a1;
    __syncthreads();
    if (t < 128) {
        float s0 = 0.f, s1 = 0.f;
        #pragma unroll
        for (int p = 0; p < 8; ++p) {
            s0 += red[0][p][t >> 2][t & 3];
            s1 += red[1][p][t >> 2][t & 3];
        }
        y0[t] = s0; y1[t] = s1;
    }
    __syncthreads();
}

__device__ __forceinline__ void gemv3(const float* __restrict__ W0, const float* __restrict__ x0,
                                      const float* __restrict__ W1, const float* __restrict__ x1,
                                      const float* __restrict__ W2, const float* __restrict__ x2,
                                      int ldw, int off, int K,
                                      float (*red)[8][32][4],
                                      float* __restrict__ y0, float* __restrict__ y1,
                                      float* __restrict__ y2, int t)
{
    const int gq = t & 31, hs = t >> 5;
    const int hn = K >> 3;
    f32x4 a0 = (f32x4){0.f,0.f,0.f,0.f}, a1 = (f32x4){0.f,0.f,0.f,0.f}, a2 = (f32x4){0.f,0.f,0.f,0.f};
    const float* Wp0 = W0 + off + (size_t)gq * 4;
    const float* Wp1 = W1 + off + (size_t)gq * 4;
    const float* Wp2 = W2 + off + (size_t)gq * 4;
    const int h0 = hs * hn;
    #pragma unroll 4
    for (int i = 0; i < hn; ++i) {
        const float4 w0 = *(const float4*)&Wp0[(size_t)(h0 + i) * ldw];
        const float4 w1 = *(const float4*)&Wp1[(size_t)(h0 + i) * ldw];
        const float4 w2 = *(const float4*)&Wp2[(size_t)(h0 + i) * ldw];
        const float v0 = x0[h0 + i], v1 = x1[h0 + i], v2 = x2[h0 + i];
        a0.x = fmaf(v0, w0.x, a0.x); a0.y = fmaf(v0, w0.y, a0.y);
        a0.z = fmaf(v0, w0.z, a0.z); a0.w = fmaf(v0, w0.w, a0.w);
        a1.x = fmaf(v1, w1.x, a1.x); a1.y = fmaf(v1, w1.y, a1.y);
        a1.z = fmaf(v1, w1.z, a1.z); a1.w = fmaf(v1, w1.w, a1.w);
        a2.x = fmaf(v2, w2.x, a2.x); a2.y = fmaf(v2, w2.y, a2.y);
        a2.z = fmaf(v2, w2.z, a2.z); a2.w = fmaf(v2, w2.w, a2.w);
    }
    *(f32x4*)&red[0][hs][gq][0] = a0;
    *(f32x4*)&red[1][hs][gq][0] = a1;
    *(f32x4*)&red[2][hs][gq][0] = a2;
    __syncthreads();
    if (t < 128) {
        float s0 = 0.f, s1 = 0.f, s2 = 0.f;
        #pragma unroll
        for (int p = 0; p < 8; ++p) {
            s0 += red[0][p][t >> 2][t & 3];
            s1 += red[1][p][t >> 2][t & 3];
            s2 += red[2][p][t >> 2][t & 3];
        }
        y0[t] = s0; y1[t] = s1; y2[t] = s2;
    }
    __syncthreads();
}

// ---------------- fused {supernode chain | NEI gather} in one launch ----------
__global__ __launch_bounds__(256) void k_gsup(
    const float* __restrict__ a_buf, const float* __restrict__ vmask,
    const ushort_t* __restrict__ vfb,
    const float* __restrict__ sf_in,
    const float* __restrict__ Wm, const float* __restrict__ bm,
    const float* __restrict__ Wm2s, const float* __restrict__ bm2s,
    const float* __restrict__ Ws2m, const float* __restrict__ bs2m,
    const float* __restrict__ Wsup, const float* __restrict__ bsup,
    const float* __restrict__ Wzm2, const float* __restrict__ bzm2,
    const float* __restrict__ Wzs1, const float* __restrict__ bzs1,
    const float* __restrict__ Wzs2, const float* __restrict__ bzs2,
    const float* __restrict__ gwih, const float* __restrict__ gwhh,
    const float* __restrict__ gbih, const float* __restrict__ gbhh,
    float* __restrict__ s2m_g, float* __restrict__ czm2_g,
    float* __restrict__ sf_out,
    const uchar_t* __restrict__ P8, const ushort_t* __restrict__ qt,
    const int* __restrict__ aadj, const int* __restrict__ badj,
    const int* __restrict__ edge, const float* __restrict__ nmask,
    ushort_t* __restrict__ nei)
{
    const int t = threadIdx.x;

    if (blockIdx.x >= B) {
        // ================= gather branch (512 blocks, 64 rows each) ========
        __shared__ ushort_t aiS[64 * Mn];
        __shared__ ushort_t eiS[64 * Mn];
        __shared__ ushort_t mkS[64 * Mn];
        const int row0 = (blockIdx.x - B) * 64;
        for (int i = t; i < 64 * Mn; i += 256) {
            const int r = i / Mn, m = i - r * Mn;
            const long g = (long)(row0 + r) * Mn + m;
            aiS[i] = (ushort_t)aadj[g];
            eiS[i] = (ushort_t)edge[badj[g]];
            mkS[i] = f2b(nmask[g]);
        }
        __syncthreads();
        #pragma unroll 1
        for (int it = 0; it < 4; ++it) {
            const int idx = it * 256 + t;
            const int r = idx >> 4, h0 = (idx & 15) * 8;
            float a8[8] = {0.f,0.f,0.f,0.f,0.f,0.f,0.f,0.f};
            #pragma unroll
            for (int m = 0; m < Mn; ++m) {
                const int ai = aiS[r * Mn + m];
                const float mk = b2f(mkS[r * Mn + m]);
                const uint2 pv = *(const uint2*)&P8[(size_t)ai * Hd + h0];
                const uint4 qv = *(const uint4*)&qt[(size_t)eiS[r * Mn + m] * Hd + h0];
                const f32x2 p01 = __builtin_amdgcn_cvt_pk_f32_fp8((int)pv.x, false);
                const f32x2 p23 = __builtin_amdgcn_cvt_pk_f32_fp8((int)pv.x, true);
                const f32x2 p45 = __builtin_amdgcn_cvt_pk_f32_fp8((int)pv.y, false);
                const f32x2 p67 = __builtin_amdgcn_cvt_pk_f32_fp8((int)pv.y, true);
                const float pf[8] = {p01[0], p01[1], p23[0], p23[1], p45[0], p45[1], p67[0], p67[1]};
                const ushort_t* qq = (const ushort_t*)&qv;
                #pragma unroll
                for (int e = 0; e < 8; ++e) {
                    const float v = pf[e] + b2f(qq[e]);
                    a8[e] = fmaf(mk, lrelu(v), a8[e]);
                }
            }
            ushort_t o8[8];
            #pragma unroll
            for (int e = 0; e < 8; ++e) o8[e] = f2b(a8[e]);
            *(uint4*)&nei[(size_t)(row0 + r) * Hd + h0] = *(const uint4*)o8;
        }
        return;
    }

    // ================= supernode branch (B blocks) =========================
    const int b = blockIdx.x;
    const int wid = t >> 6, lane = t & 63;
    __shared__ float red[3][8][32][4];
    __shared__ float att0[256], att1[256];
    __shared__ float sfl[128], tbA[128], tbB[128], mv[256];
    __shared__ float ms2[128], s2ml[128], ssl[128], hsl[128];
    __shared__ float tmp1[128], tmp2[128], tmp3[128];
    __shared__ float gib[384], ghb[384];
    __shared__ float saS[2];
    __shared__ float lm[4][2], ls[4][2];

    const float v0 = a_buf[(size_t)b * 512 + t];
    const float v1 = a_buf[(size_t)b * 512 + 256 + t];
    const float vm = vmask[b * Nv + t];
    float m0 = v0, m1 = v1;
    #pragma unroll
    for (int o = 1; o < 64; o <<= 1) {
        m0 = fmaxf(m0, __shfl_xor(m0, o));
        m1 = fmaxf(m1, __shfl_xor(m1, o));
    }
    if (lane == 0) { lm[wid][0] = m0; lm[wid][1] = m1; }
    __syncthreads();
    m0 = fmaxf(fmaxf(lm[0][0], lm[1][0]), fmaxf(lm[2][0], lm[3][0]));
    m1 = fmaxf(fmaxf(lm[0][1], lm[1][1]), fmaxf(lm[2][1], lm[3][1]));
    const float e0v = __expf(v0 - m0) * vm;
    const float e1v = __expf(v1 - m1) * vm;
    float s0 = e0v, s1 = e1v;
    #pragma unroll
    for (int o = 1; o < 64; o <<= 1) {
        s0 += __shfl_xor(s0, o);
        s1 += __shfl_xor(s1, o);
    }
    if (lane == 0) { ls[wid][0] = s0; ls[wid][1] = s1; }
    if (t < 128) sfl[t] = sf_in[b * Hd + t];
    __syncthreads();
    s0 = ls[0][0] + ls[1][0] + ls[2][0] + ls[3][0];
    s1 = ls[0][1] + ls[1][1] + ls[2][1] + ls[3][1];
    att0[t] = e0v * frcp(s0 + 1e-6f);
    att1[t] = e1v * frcp(s1 + 1e-6f);
    if (t == 0) { saS[0] = s0 * frcp(s0 + 1e-6f); saS[1] = s1 * frcp(s1 + 1e-6f); }
    __syncthreads();

    {
        const int hq = t & 31, ns = t >> 5;
        f32x4 a0 = (f32x4){0.f,0.f,0.f,0.f}, a1 = (f32x4){0.f,0.f,0.f,0.f};
        const ushort_t* base = vfb + (size_t)b * Nv * Hd + hq * 4;
        #pragma unroll 8
        for (int i = 0; i < 32; ++i) {
            const int n = ns * 32 + i;
            float xv[4];
            b2f4(*(const uint2*)&base[(size_t)n * Hd], xv);
            const float w0 = att0[n], w1 = att1[n];
            a0.x = fmaf(w0, xv[0], a0.x); a0.y = fmaf(w0, xv[1], a0.y);
            a0.z = fmaf(w0, xv[2], a0.z); a0.w = fmaf(w0, xv[3], a0.w);
            a1.x = fmaf(w1, xv[0], a1.x); a1.y = fmaf(w1, xv[1], a1.y);
            a1.z = fmaf(w1, xv[2], a1.z); a1.w = fmaf(w1, xv[3], a1.w);
        }
        *(f32x4*)&red[0][ns][hq][0] = a0;
        *(f32x4*)&red[1][ns][hq][0] = a1;
        __syncthreads();
        if (t < 128) {
            float u0 = 0.f, u1 = 0.f;
            #pragma unroll
            for (int p = 0; p < 8; ++p) {
                u0 += red[0][p][t >> 2][t & 3];
                u1 += red[1][p][t >> 2][t & 3];
            }
            tbA[t] = u0; tbB[t] = u1;
        }
        __syncthreads();
    }

    gemv2(Wm, tbA, Wm + Hd * Hd, tbB, Hd, 0, Hd, red, mv, mv + 128, t);
    mv[t] += saS[t >> 7] * bm[t];
    __syncthreads();

    gemv1(Wm2s, mv, Hd, 0, 2 * Hd, red, tmp1, t);
    if (t < 128) ms2[t] = ftanh(tmp1[t] + bm2s[t]);
    __syncthreads();

    gemv2(Ws2m, sfl, Wsup, sfl, Hd, 0, Hd, red, tmp1, tmp2, t);
    if (t < 128) {
        const float v = ftanh(tmp1[t] + bs2m[t]);
        s2ml[t] = v; s2m_g[b * Hd + t] = v;
        ssl[t] = ftanh(tmp2[t] + bsup[t]);
    }
    __syncthreads();

    gemv3(Wzm2, s2ml, Wzs1, ssl, Wzs2, ms2, Hd, 0, Hd, red, tmp1, tmp2, tmp3, t);
    if (t < 128) {
        czm2_g[b * Hd + t] = tmp1[t] + bzm2[t];
        const float zs = sigmoidf(tmp2[t] + bzs1[t] + tmp3[t] + bzs2[t]);
        hsl[t] = (1.f - zs) * ssl[t] + zs * ms2[t];
    }
    __syncthreads();

    #pragma unroll 1
    for (int c = 0; c < 3; ++c)
        gemv2(gwih, hsl, gwhh, sfl, 3 * Hd, c * Hd, Hd, red, gib + c * Hd, ghb + c * Hd, t);
    if (t < 128) {
        const float r = sigmoidf(gib[t] + gbih[t] + ghb[t] + gbhh[t]);
        const float z = sigmoidf(gib[128 + t] + gbih[128 + t] + ghb[128 + t] + gbhh[128 + t]);
        const float n = ftanh(gib[256 + t] + gbih[256 + t] + r * (ghb[256 + t] + gbhh[256 + t]));
        sf_out[b * Hd + t] = (1.f - z) * n + z * sfl[t];
    }
}

// ---------------- MEGA: 32-row tile, separate MS/HID buffers, 3 barriers ------
__global__ __launch_bounds__(256) void k_mega(
    const ushort_t* __restrict__ vfb,
    const ushort_t* __restrict__ nei,
    const ushort_t* __restrict__ wt_u1,    // 128 cols, Kpad 256
    const ushort_t* __restrict__ wt_zm1,   // 128 cols, Kpad 128
    const ushort_t* __restrict__ wt_rz,    // 256 cols, Kpad 256 (k<128 wih/HID, k>=128 whh/VF)
    const ushort_t* __restrict__ wt_inn,   // 128 cols, Kpad 128 (HID)
    const ushort_t* __restrict__ wt_hn,    // 128 cols, Kpad 128 (VF)
    const float* __restrict__ u1b,
    const float* __restrict__ zm1b,
    const float* __restrict__ bih, const float* __restrict__ bhh,
    const float* __restrict__ czm2, const float* __restrict__ s2m,
    void* __restrict__ outv, const int finalFp32)
{
    const int t = threadIdx.x;
    const int lane = t & 63;
    const int wn = t >> 6;
    const int lr = lane & 15, lg = lane >> 4;
    const int row0 = blockIdx.x * 32;
    const int b = row0 >> 8;

    __shared__ ushort_t As[32 * 256];       // 16 KB (VF | NEI, read-only)
    __shared__ ushort_t Ms[32 * 128];       // 8 KB  (MS)
    __shared__ ushort_t Hs[32 * 128];       // 8 KB  (HID)

    // ---- stage VF -> cols 0..127, NEI -> cols 128..255 (full coverage) ----
    {
        const int r_st = t >> 3, q8 = t & 7;
        const ushort_t* srcV = vfb + (size_t)(row0 + r_st) * Hd + q8 * 16;
        const ushort_t* srcN = nei + (size_t)(row0 + r_st) * Hd + q8 * 16;
        uint4 v0 = ((const uint4*)srcV)[0];
        uint4 v1 = ((const uint4*)srcV)[1];
        uint4 n0 = ((const uint4*)srcN)[0];
        uint4 n1 = ((const uint4*)srcN)[1];
        int bV0 = (r_st * 512 + q8 * 32)            ^ ((r_st & 7) << 4);
        int bV1 = (r_st * 512 + q8 * 32 + 16)       ^ ((r_st & 7) << 4);
        int bN0 = (r_st * 512 + 256 + q8 * 32)      ^ ((r_st & 7) << 4);
        int bN1 = (r_st * 512 + 256 + q8 * 32 + 16) ^ ((r_st & 7) << 4);
        *(uint4*)((char*)As + bV0) = v0;
        *(uint4*)((char*)As + bV1) = v1;
        *(uint4*)((char*)As + bN0) = n0;
        *(uint4*)((char*)As + bN1) = n1;
    }
    __syncthreads();                        // (1) stage done

    f32x4 acc[2][2];

#define ZERO_ACC2() { _Pragma("unroll") for (int i = 0; i < 2; ++i) _Pragma("unroll") for (int j = 0; j < 2; ++j) acc[i][j] = (f32x4){0.f,0.f,0.f,0.f}; }
#define AF_L32(LC) (*(const short8*)((const char*)As + ((((mf * 16 + lr) * 512 + ((LC) + lg * 8) * 2)) ^ ((lr & 7) << 4))))
#define AF_MH(BUF, LC) (*(const short8*)((const char*)(BUF) + ((((mf * 16 + lr) * 256 + ((LC) + lg * 8) * 2)) ^ ((lr & 7) << 4))))
#define GEMM_PASS32(WG, KPADW, KTOT, A_EXPR) { \
        ZERO_ACC2(); \
        _Pragma("unroll") \
        for (int kk = 0; kk < (KTOT); kk += 32) { \
            short8 af[2], bfv[2]; \
            _Pragma("unroll") \
            for (int nf = 0; nf < 2; ++nf) \
                bfv[nf] = *(const short8*)((WG) + (size_t)(wn * 32 + nf * 16 + lr) * (KPADW) + kk + lg * 8); \
            _Pragma("unroll") \
            for (int mf = 0; mf < 2; ++mf) \
                af[mf] = (A_EXPR); \
            _Pragma("unroll") \
            for (int mf = 0; mf < 2; ++mf) \
                _Pragma("unroll") \
                for (int nf = 0; nf < 2; ++nf) \
                    acc[mf][nf] = __builtin_amdgcn_mfma_f32_16x16x32_bf16(af[mf], bfv[nf], acc[mf][nf], 0, 0, 0); \
        } }

    // ---- U1: MS = lrelu([VF|NEI]@Wu1 + b) -> Ms (fresh buffer, no pre-barrier)
    GEMM_PASS32(wt_u1, 256, 256, AF_L32(kk));
    #pragma unroll
    for (int mf = 0; mf < 2; ++mf)
        #pragma unroll
        for (int nf = 0; nf < 2; ++nf) {
            const int c = wn * 32 + nf * 16 + lr;
            const float bb = u1b[c];
            #pragma unroll
            for (int reg = 0; reg < 4; ++reg) {
                const int row = mf * 16 + lg * 4 + reg;
                int byte = (row * 256 + c * 2) ^ ((row & 7) << 4);
                *(ushort_t*)((char*)Ms + byte) = f2b(lrelu(acc[mf][nf][reg] + bb));
            }
        }
    __syncthreads();                        // (2) MS ready

    // ---- ZMAIN: z = sig(MS@Wzm1 + b + czm2); HID = (1-z)*MS + z*s2m -> Hs ----
    GEMM_PASS32(wt_zm1, 128, 128, AF_MH(Ms, kk));
    #pragma unroll
    for (int mf = 0; mf < 2; ++mf)
        #pragma unroll
        for (int nf = 0; nf < 2; ++nf) {
            const int c = wn * 32 + nf * 16 + lr;
            const float bb = zm1b[c] + czm2[b * Hd + c];
            const float s2 = s2m[b * Hd + c];
            #pragma unroll
            for (int reg = 0; reg < 4; ++reg) {
                const int row = mf * 16 + lg * 4 + reg;
                int byte = (row * 256 + c * 2) ^ ((row & 7) << 4);
                const float ms = b2f(*(const ushort_t*)((const char*)Ms + byte));
                const float z = sigmoidf(acc[mf][nf][reg] + bb);
                *(ushort_t*)((char*)Hs + byte) = f2b((1.f - z) * ms + z * s2);
            }
        }
    __syncthreads();                        // (3) HID ready — no more barriers

    // ---- GRU gates (packed bf16 intermediates) ----
    uint_t innp[2][2][2], hnp[2][2][2];
    GEMM_PASS32(wt_inn, 128, 128, AF_MH(Hs, kk));
    #pragma unroll
    for (int mf = 0; mf < 2; ++mf)
        #pragma unroll
        for (int nf = 0; nf < 2; ++nf) {
            const int c = wn * 32 + nf * 16 + lr;
            const float bb = bih[256 + c];
            innp[mf][nf][0] = pk2(acc[mf][nf][0] + bb, acc[mf][nf][1] + bb);
            innp[mf][nf][1] = pk2(acc[mf][nf][2] + bb, acc[mf][nf][3] + bb);
        }
    GEMM_PASS32(wt_hn, 128, 128, AF_L32(kk));
    #pragma unroll
    for (int mf = 0; mf < 2; ++mf)
        #pragma unroll
        for (int nf = 0; nf < 2; ++nf) {
            const int c = wn * 32 + nf * 16 + lr;
            const float bb = bhh[256 + c];
            hnp[mf][nf][0] = pk2(acc[mf][nf][0] + bb, acc[mf][nf][1] + bb);
            hnp[mf][nf][1] = pk2(acc[mf][nf][2] + bb, acc[mf][nf][3] + bb);
        }
    // r = sig([HID|VF]@Wr + b); n = tanh(inn + r*hn)
    GEMM_PASS32(wt_rz, 256, 256, (kk < 128) ? AF_MH(Hs, kk) : AF_L32(kk - 128));
    #pragma unroll
    for (int mf = 0; mf < 2; ++mf)
        #pragma unroll
        for (int nf = 0; nf < 2; ++nf) {
            const int c = wn * 32 + nf * 16 + lr;
            const float bb = bih[c] + bhh[c];
            const float r0 = sigmoidf(acc[mf][nf][0] + bb);
            const float r1 = sigmoidf(acc[mf][nf][1] + bb);
            const float r2 = sigmoidf(acc[mf][nf][2] + bb);
            const float r3 = sigmoidf(acc[mf][nf][3] + bb);
            const float n0 = ftanh(upk_lo(innp[mf][nf][0]) + r0 * upk_lo(hnp[mf][nf][0]));
            const float n1 = ftanh(upk_hi(innp[mf][nf][0]) + r1 * upk_hi(hnp[mf][nf][0]));
            const float n2 = ftanh(upk_lo(innp[mf][nf][1]) + r2 * upk_lo(hnp[mf][nf][1]));
            const float n3 = ftanh(upk_hi(innp[mf][nf][1]) + r3 * upk_hi(hnp[mf][nf][1]));
            innp[mf][nf][0] = pk2(n0, n1);
            innp[mf][nf][1] = pk2(n2, n3);
        }
    // z + combine + store (hprev from As VF region, cols 0..127)
    GEMM_PASS32(wt_rz + 128 * 256, 256, 256, (kk < 128) ? AF_MH(Hs, kk) : AF_L32(kk - 128));
    #pragma unroll
    for (int mf = 0; mf < 2; ++mf)
        #pragma unroll
        for (int nf = 0; nf < 2; ++nf) {
            const int c = wn * 32 + nf * 16 + lr;
            const float bb = bih[128 + c] + bhh[128 + c];
            #pragma unroll
            for (int reg = 0; reg < 4; ++reg) {
                const int rl = mf * 16 + lg * 4 + reg;
                const float z = sigmoidf(acc[mf][nf][reg] + bb);
                const uint_t np = innp[mf][nf][reg >> 1];
                const float n = (reg & 1) ? upk_hi(np) : upk_lo(np);
                int byte = (rl * 512 + c * 2) ^ ((rl & 7) << 4);
                const float h = b2f(*(const ushort_t*)((const char*)As + byte));
                const float o = (1.f - z) * n + z * h;
                const size_t oidx = (size_t)(row0 + rl) * Hd + c;
                if (finalFp32) ((float*)outv)[oidx] = o;
                else           ((ushort_t*)outv)[oidx] = f2b(o);
            }
        }
#undef GEMM_PASS32
#undef ZERO_ACC2
#undef AF_L32
#undef AF_MH
}

// sf[b,h] = sum_n vf[b,n,h]*vmask[b,n]  (bf16 vf)
__global__ __launch_bounds__(256) void k_sfv(const ushort_t* __restrict__ vfb,
                                             const float* __restrict__ vmask,
                                             float* __restrict__ sf)
{
    const int b = blockIdx.x, t = threadIdx.x;
    __shared__ float vm[256];
    __shared__ float red[8][32][4];
    vm[t] = vmask[b * Nv + t];
    __syncthreads();
    const int hq = t & 31, ns = t >> 5;
    f32x4 acc = (f32x4){0.f,0.f,0.f,0.f};
    const ushort_t* base = vfb + (size_t)b * Nv * Hd + hq * 4;
    #pragma unroll 8
    for (int i = 0; i < 32; ++i) {
        const int n = ns * 32 + i;
        float xv[4];
        b2f4(*(const uint2*)&base[(size_t)n * Hd], xv);
        const float w = vm[n];
        acc.x = fmaf(w, xv[0], acc.x); acc.y = fmaf(w, xv[1], acc.y);
        acc.z = fmaf(w, xv[2], acc.z); acc.w = fmaf(w, xv[3], acc.w);
    }
    *(f32x4*)&red[ns][hq][0] = acc;
    __syncthreads();
    if (t < 128) {
        float s = 0.f;
        #pragma unroll
        for (int p = 0; p < 8; ++p) s += red[p][t >> 2][t & 3];
        sf[b * Hd + t] = s;
    }
}

extern "C" void kernel_launch(void* const* d_in, const int* in_sizes, int n_in,
                              void* d_out, int out_size, void* d_ws, size_t ws_size,
                              hipStream_t stream)
{
    (void)in_sizes; (void)n_in; (void)out_size;

    const float* vertex_mask = (const float*)d_in[1];
    const int*   vertex      = (const int*)d_in[2];
    const int*   edge        = (const int*)d_in[3];
    const int*   atom_adj    = (const int*)d_in[4];
    const int*   bond_adj    = (const int*)d_in[5];
    const float* nbs_mask    = (const float*)d_in[6];
    const float* init_atom   = (const float*)d_in[7];
    const float* init_bond   = (const float*)d_in[8];
    const float* emb_w  = (const float*)d_in[9];
    const float* emb_b  = (const float*)d_in[10];
    const float* Wa_w   = (const float*)d_in[11];
    const float* Wa_b   = (const float*)d_in[12];
    const float* Wbmm_w = (const float*)d_in[13];
    const float* Wbmm_b = (const float*)d_in[14];
    const float* Wm_w   = (const float*)d_in[15];
    const float* Wm_b   = (const float*)d_in[16];
    const float* Wm2s_w = (const float*)d_in[17];
    const float* Wm2s_b = (const float*)d_in[18];
    const float* Ws2m_w = (const float*)d_in[19];
    const float* Ws2m_b = (const float*)d_in[20];
    const float* Wsup_w = (const float*)d_in[21];
    const float* Wsup_b = (const float*)d_in[22];
    const float* Wzm1_w = (const float*)d_in[23];
    const float* Wzm1_b = (const float*)d_in[24];
    const float* Wzm2_w = (const float*)d_in[25];
    const float* Wzm2_b = (const float*)d_in[26];
    const float* Wzs1_w = (const float*)d_in[27];
    const float* Wzs1_b = (const float*)d_in[28];
    const float* Wzs2_w = (const float*)d_in[29];
    const float* Wzs2_b = (const float*)d_in[30];
    const float* U2_w   = (const float*)d_in[31];
    const float* U2_b   = (const float*)d_in[32];
    const float* U1_w   = (const float*)d_in[33];
    const float* U1_b   = (const float*)d_in[34];
    const float* gm_wih = (const float*)d_in[35];
    const float* gm_whh = (const float*)d_in[36];
    const float* gm_bih = (const float*)d_in[37];
    const float* gm_bhh = (const float*)d_in[38];
    const float* gs_wih = (const float*)d_in[39];
    const float* gs_whh = (const float*)d_in[40];
    const float* gs_bih = (const float*)d_in[41];
    const float* gs_bhh = (const float*)d_in[42];

    const size_t MB = 1u << 20;
    if (ws_size < 40 * MB) return;

    char* base = (char*)d_ws;
    ushort_t* VF0 = (ushort_t*)base;               // 8 MB
    ushort_t* VF1 = (ushort_t*)(base + 8 * MB);    // 8 MB
    uchar_t*  P8  = (uchar_t*)(base + 16 * MB);    // 4 MB (fp8 e4m3)
    ushort_t* NEI = (ushort_t*)(base + 20 * MB);   // 8 MB
    ushort_t* WT  = (ushort_t*)(base + 28 * MB);   // ~0.82 MB
    ushort_t* QT  = (ushort_t*)(base + 30 * MB);   // 3*12*128 bf16
    float*    S   = (float*)(base + 31 * MB);

    float* sfA    = S;
    float* sfB    = S + 16384;
    float* a_buf  = S + 32768;
    float* s2m    = S + 98304;
    float* c_zm2  = S + 114688;

    float* X1 = (float*)d_out;
    float* sf_final = X1 + (size_t)BN * Hd;

    const int OFF_EMB = 0;
    const int PERD = 98304;
    const int OFF_L0 = 16384;
    const int OFF_RZ = OFF_L0 + 3 * PERD;
    const int OFF_NH = OFF_RZ + 65536;

    PrepJobs PJ;
    int nj = 0, blk0 = 0;
    auto addJob = [&](const float* W, int K, int ldw, long sStride, int nPer,
                      int Kspan, int KpadRow, int kDst, int ncols, int outOff) {
        PrepJob& J = PJ.j[nj++];
        J.W = W; J.K = K; J.ldw = ldw; J.sliceStride = sStride; J.nPerSlice = nPer;
        J.Kspan = Kspan; J.KpadRow = KpadRow; J.kDst = kDst;
        J.total = ncols * Kspan; J.outOff = outOff; J.blockStart = blk0;
        blk0 += (J.total + 255) / 256;
    };
    addJob(emb_w, AFd, Hd, 0, Hd, 128, 128, 0, 128, OFF_EMB);
    for (int d = 0; d < Dd; ++d) {
        const int o = OFF_L0 + d * PERD;
        addJob(Wa_w + (long)d * Kk * Hd * Hd, Hd, Hd, (long)Hd * Hd, Hd, 128, 128, 0, 256, o);
        addJob(U2_w + (long)d * (Hd + BFd) * Hd, Hd, Hd, 0, Hd, 128, 128, 0, 128, o + 32768);
        addJob(U1_w + (long)d * 2 * Hd * Hd, 2 * Hd, Hd, 0, Hd, 256, 256, 0, 128, o + 49152);
        addJob(Wzm1_w + (long)d * Hd * Hd, Hd, Hd, 0, Hd, 128, 128, 0, 128, o + 81920);
    }
    addJob(gm_wih, Hd, 3 * Hd, 0, 256, 128, 256, 0,   256, OFF_RZ);
    addJob(gm_whh, Hd, 3 * Hd, 0, 256, 128, 256, 128, 256, OFF_RZ);
    addJob(gm_wih + 256, Hd, 3 * Hd, 0, 128, 128, 128, 0, 128, OFF_NH);
    addJob(gm_whh + 256, Hd, 3 * Hd, 0, 128, 128, 128, 0, 128, OFF_NH + 16384);
    PJ.nJobs = nj;
    k_prep_all<<<dim3(blk0), dim3(256), 0, stream>>>(PJ, WT);
    k_qtab<<<dim3(Dd), dim3(256), 0, stream>>>(init_bond, U2_w, QT);

    const dim3 blk(256);
    const dim3 g1(BN / 64, 1);
    const dim3 g32(BN / 32, 1);

    // embed -> VF0 (bf16)
    mgemm<EPI_LRELU, false, true><<<g1, blk, 0, stream>>>(
        init_atom, AFd, AFd, vertex,
        WT + OFF_EMB, 128, emb_b, VF0, Hd);
    k_sfv<<<dim3(B), blk, 0, stream>>>(VF0, vertex_mask, sfA);

    for (int d = 0; d < Dd; ++d) {
        ushort_t* vin  = (d & 1) ? VF1 : VF0;
        ushort_t* vout = (d & 1) ? VF0 : VF1;
        float* sin  = (d & 1) ? sfB : sfA;
        float* sout = (d == Dd - 1) ? sf_final : ((d & 1) ? sfA : sfB);

        const int o = OFF_L0 + d * PERD;

        // scores (y=0: both k slices, A staged once) + P projection fp8 (y=1)
        k_tdp<<<dim3(BN / 64, 2), blk, 0, stream>>>(
            vin, WT + o,
            Wa_b + (long)d * Kk * Hd, U2_b + (long)d * Hd,
            sin, Wbmm_w + (long)d * Kk * Hd, Wbmm_b + (long)d * Kk,
            a_buf, P8);

        // fused {supernode chain | NEI gather} — independent work, one launch
        k_gsup<<<dim3(B + BN / 64), blk, 0, stream>>>(
            a_buf, vertex_mask, vin, sin,
            Wm_w + (long)d * Kk * Hd * Hd, Wm_b + (long)d * Kk * Hd,
            Wm2s_w + (long)d * Kk * Hd * Hd, Wm2s_b + (long)d * Hd,
            Ws2m_w + (long)d * Hd * Hd, Ws2m_b + (long)d * Hd,
            Wsup_w + (long)d * Hd * Hd, Wsup_b + (long)d * Hd,
            Wzm2_w + (long)d * Hd * Hd, Wzm2_b + (long)d * Hd,
            Wzs1_w + (long)d * Hd * Hd, Wzs1_b + (long)d * Hd,
            Wzs2_w + (long)d * Hd * Hd, Wzs2_b + (long)d * Hd,
            gs_wih, gs_whh, gs_bih, gs_bhh,
            s2m, c_zm2, sout,
            P8, QT + (size_t)d * 12 * Hd,
            atom_adj, bond_adj, edge, nbs_mask, NEI);

        // MEGA: U1 -> ZMAIN -> GRU main -> vf_out (32-row, 3 barriers)
        k_mega<<<g32, blk, 0, stream>>>(
            vin, NEI,
            WT + o + 49152, WT + o + 81920,
            WT + OFF_RZ, WT + OFF_NH, WT + OFF_NH + 16384,
            U1_b + (long)d * Hd, Wzm1_b + (long)d * Hd,
            gm_bih, gm_bhh,
            c_zm2, s2m,
            (d == Dd - 1) ? (void*)X1 : (void*)vout, (d == Dd - 1) ? 1 : 0);
    }
}